// Round 1
// baseline (2861.167 us; speedup 1.0000x reference)
//
#include <hip/hip_runtime.h>

#define NB 16
#define NP 2048
#define KNN 20

// monotonic float->uint key (handles tiny negative dists from fp cancellation)
__device__ __forceinline__ unsigned fkey(float f) {
  unsigned u = __float_as_uint(f);
  return (u & 0x80000000u) ? ~u : (u | 0x80000000u);
}

__device__ __forceinline__ unsigned long long bfly_min(unsigned long long key) {
  #pragma unroll
  for (int m = 1; m < 64; m <<= 1) {
    unsigned long long o = __shfl_xor(key, m, 64);
    if (o < key) key = o;
  }
  return key;
}

// ---------------- EdgeConv1: 3-dim kNN + MLP(6->64->64) + max ----------------
__global__ __launch_bounds__(256) void ec1_kernel(
    const float* __restrict__ pos, const float* __restrict__ w1,
    const float* __restrict__ b1, const float* __restrict__ w2,
    const float* __restrict__ b2, float* __restrict__ out1)
{
  __shared__ float px[NP], py[NP], pz[NP];
  __shared__ float sw1[6*64], sw2[64*64], sb1[64], sb2[64];
  const int b = blockIdx.x, t = threadIdx.x;
  const int wave = t >> 6, lane = t & 63;
  const float* pb = pos + (size_t)b * NP * 3;
  for (int k = t; k < NP; k += 256) {
    px[k] = pb[3*k]; py[k] = pb[3*k+1]; pz[k] = pb[3*k+2];
  }
  for (int k = t; k < 6*64; k += 256) sw1[k] = w1[k];
  for (int k = t; k < 64*64; k += 256) sw2[k] = w2[k];
  if (t < 64) { sb1[t] = b1[t]; sb2[t] = b2[t]; }
  __syncthreads();

  for (int p = 0; p < 8; ++p) {
    const int i = blockIdx.y * 32 + wave * 8 + p;
    const float xix = px[i], xiy = py[i], xiz = pz[i];
    const float ni = xix*xix + xiy*xiy + xiz*xiz;
    float d[32];
    #pragma unroll
    for (int tt = 0; tt < 32; ++tt) {
      const int j = tt*64 + lane;
      const float ax = px[j], ay = py[j], az = pz[j];
      const float nj = ax*ax + ay*ay + az*az;
      const float dot = xix*ax + xiy*ay + xiz*az;
      d[tt] = ni + nj - 2.0f*dot;
    }
    float omax = 0.0f;  // outputs are post-relu (>=0)
    for (int n = 0; n < KNN; ++n) {
      // wave-wide argmin (exact dist, ties -> smallest index, matches top_k)
      float mind = 3.0e38f; int mint = 0;
      #pragma unroll
      for (int tt = 0; tt < 32; ++tt) {
        const bool c = d[tt] < mind; mind = c ? d[tt] : mind; mint = c ? tt : mint;
      }
      unsigned long long key =
          ((unsigned long long)fkey(mind) << 32) | (unsigned)(mint*64 + lane);
      key = bfly_min(key);
      const int jstar = (int)(key & 0xffffffffull);
      #pragma unroll
      for (int tt = 0; tt < 32; ++tt)
        if (tt*64 + lane == jstar) d[tt] = 3.0e38f;

      // MLP on edge (i, jstar)
      const float xjx = px[jstar], xjy = py[jstar], xjz = pz[jstar];
      const float e3 = xjx - xix, e4 = xjy - xiy, e5 = xjz - xiz;
      float h1 = sb1[lane];
      h1 = fmaf(xix, sw1[0*64+lane], h1);
      h1 = fmaf(xiy, sw1[1*64+lane], h1);
      h1 = fmaf(xiz, sw1[2*64+lane], h1);
      h1 = fmaf(e3,  sw1[3*64+lane], h1);
      h1 = fmaf(e4,  sw1[4*64+lane], h1);
      h1 = fmaf(e5,  sw1[5*64+lane], h1);
      h1 = fmaxf(h1, 0.0f);
      float h2 = sb2[lane];
      #pragma unroll 8
      for (int c = 0; c < 64; ++c)
        h2 = fmaf(__shfl(h1, c, 64), sw2[c*64+lane], h2);
      omax = fmaxf(omax, fmaxf(h2, 0.0f));
    }
    out1[((size_t)b*NP + i)*64 + lane] = omax;
  }
}

// ---------------- row sq-norms of out1 (same fmaf order as dot) --------------
__global__ __launch_bounds__(256) void norms_kernel(
    const float* __restrict__ x, float* __restrict__ nrm)
{
  const int id = blockIdx.x * 256 + threadIdx.x;
  const float* r = x + (size_t)id * 64;
  float s = 0.f;
  #pragma unroll
  for (int c = 0; c < 64; ++c) s = fmaf(r[c], r[c], s);
  nrm[id] = s;
}

// ---------------- EdgeConv2 kNN: 64-dim dists + top-20 ----------------------
__device__ __forceinline__ void topk20_ec2(float (&d)[32], int lane, int* __restrict__ dst) {
  for (int n = 0; n < KNN; ++n) {
    float mind = 3.0e38f; int mint = 0;
    #pragma unroll
    for (int tt = 0; tt < 32; ++tt) {
      const bool c = d[tt] < mind; mind = c ? d[tt] : mind; mint = c ? tt : mint;
    }
    const int jl = ((mint >> 1)*128) + ((mint & 1)*64) + lane;
    unsigned long long key = ((unsigned long long)fkey(mind) << 32) | (unsigned)jl;
    key = bfly_min(key);
    const int jstar = (int)(key & 0xffffffffull);
    #pragma unroll
    for (int tt = 0; tt < 32; ++tt) {
      const int jt = ((tt >> 1)*128) + ((tt & 1)*64) + lane;
      if (jt == jstar) d[tt] = 3.0e38f;
    }
    if (lane == 0) dst[n] = jstar;
  }
}

__global__ __launch_bounds__(256) void ec2knn_kernel(
    const float* __restrict__ x, const float* __restrict__ nrm, int* __restrict__ knn)
{
  __shared__ float chunk[128*65];   // pad 64->65: conflict-free strided reads
  __shared__ float sxi[8*64];
  __shared__ float snrm[128];
  const int b = blockIdx.x, t = threadIdx.x;
  const int wave = t >> 6, lane = t & 63;
  const int base = blockIdx.y * 8;
  const float* xb = x + (size_t)b * NP * 64;
  for (int k = t; k < 8*64; k += 256) sxi[k] = xb[(size_t)base*64 + k];
  const int i0 = base + wave*2, i1 = i0 + 1;
  const float ni0 = nrm[b*NP + i0], ni1 = nrm[b*NP + i1];
  float d0[32], d1[32];
  #pragma unroll
  for (int ch = 0; ch < 16; ++ch) {
    __syncthreads();
    const float* src = xb + (size_t)ch * 128 * 64;
    for (int k = t*4; k < 128*64; k += 1024) {
      const float4 v = *(const float4*)(src + k);
      const int j = k >> 6, c = k & 63;
      float* dstp = &chunk[j*65 + c];
      dstp[0] = v.x; dstp[1] = v.y; dstp[2] = v.z; dstp[3] = v.w;
    }
    if (t < 128) snrm[t] = nrm[b*NP + ch*128 + t];
    __syncthreads();
    float a00 = 0.f, a01 = 0.f, a10 = 0.f, a11 = 0.f;
    #pragma unroll 4
    for (int c = 0; c < 64; ++c) {
      const float xj0 = chunk[lane*65 + c];
      const float xj1 = chunk[(64 + lane)*65 + c];
      const float x0 = sxi[(wave*2)*64 + c];
      const float x1 = sxi[(wave*2 + 1)*64 + c];
      a00 = fmaf(x0, xj0, a00);
      a01 = fmaf(x0, xj1, a01);
      a10 = fmaf(x1, xj0, a10);
      a11 = fmaf(x1, xj1, a11);
    }
    const float nj0 = snrm[lane], nj1 = snrm[64 + lane];
    d0[2*ch]     = ni0 + nj0 - 2.0f*a00;
    d0[2*ch + 1] = ni0 + nj1 - 2.0f*a01;
    d1[2*ch]     = ni1 + nj0 - 2.0f*a10;
    d1[2*ch + 1] = ni1 + nj1 - 2.0f*a11;
  }
  topk20_ec2(d0, lane, knn + ((size_t)b*NP + i0)*KNN);
  topk20_ec2(d1, lane, knn + ((size_t)b*NP + i1)*KNN);
}

// ---------------- EdgeConv2 MLP: (128->128) + max over 20 neighbors ---------
__global__ __launch_bounds__(256) void ec2mlp_kernel(
    const float* __restrict__ x, const int* __restrict__ knn,
    const float* __restrict__ w, const float* __restrict__ bias,
    float* __restrict__ out2)
{
  __shared__ float sw[128*128];  // 64 KB
  const int b = blockIdx.x, t = threadIdx.x;
  const int wave = t >> 6, lane = t & 63;
  for (int k = t; k < 128*128; k += 256) sw[k] = w[k];
  __syncthreads();
  const float bl0 = bias[lane], bl1 = bias[64 + lane];
  const float* xb = x + (size_t)b * NP * 64;
  for (int p = 0; p < 8; ++p) {
    const int i = blockIdx.y*32 + wave*8 + p;
    const float xi = xb[(size_t)i*64 + lane];
    // xi-part of matmul is identical for all 20 edges: hoist it
    float base0 = bl0, base1 = bl1;
    #pragma unroll 4
    for (int c = 0; c < 64; ++c) {
      const float xic = __shfl(xi, c, 64);
      base0 = fmaf(xic, sw[c*128 + lane], base0);
      base1 = fmaf(xic, sw[c*128 + 64 + lane], base1);
    }
    float m0 = 0.f, m1v = 0.f;  // relu via 0-init
    const int* ip = knn + ((size_t)b*NP + i)*KNN;
    for (int q = 0; q < 5; ++q) {
      float dx[4], acc0[4], acc1[4];
      #pragma unroll
      for (int u = 0; u < 4; ++u) {
        const int j = ip[q*4 + u];
        dx[u] = xb[(size_t)j*64 + lane] - xi;
        acc0[u] = base0; acc1[u] = base1;
      }
      #pragma unroll 2
      for (int c = 0; c < 64; ++c) {
        const float w0  = sw[(64 + c)*128 + lane];
        const float w1v = sw[(64 + c)*128 + 64 + lane];
        #pragma unroll
        for (int u = 0; u < 4; ++u) {
          const float e = __shfl(dx[u], c, 64);
          acc0[u] = fmaf(e, w0, acc0[u]);
          acc1[u] = fmaf(e, w1v, acc1[u]);
        }
      }
      #pragma unroll
      for (int u = 0; u < 4; ++u) {
        m0  = fmaxf(m0,  acc0[u]);
        m1v = fmaxf(m1v, acc1[u]);
      }
    }
    out2[((size_t)b*NP + i)*128 + lane] = m0;
    out2[((size_t)b*NP + i)*128 + 64 + lane] = m1v;
  }
}

// ---------------- m1: relu([out1|out2] @ W192x512 + b), mean-pool -----------
__global__ __launch_bounds__(256) void m1pool_kernel(
    const float* __restrict__ o1, const float* __restrict__ o2,
    const float* __restrict__ w, const float* __restrict__ bias,
    float* __restrict__ pool)
{
  __shared__ float sw[192*64];  // 48 KB col-tile
  const int b = blockIdx.x, t = threadIdx.x;
  const int wave = t >> 6, lane = t & 63;
  const int rbase = blockIdx.y * 64 + wave * 16;
  for (int ct = 0; ct < 8; ++ct) {
    __syncthreads();
    for (int k = t; k < 192*64; k += 256)
      sw[k] = w[(size_t)(k >> 6)*512 + ct*64 + (k & 63)];
    __syncthreads();
    const float bb = bias[ct*64 + lane];
    float acc = 0.f;
    for (int r4 = 0; r4 < 4; ++r4) {
      const int r = rbase + r4*4;
      const float* o1r = o1 + ((size_t)b*NP + r)*64;
      const float* o2r = o2 + ((size_t)b*NP + r)*128;
      float A0[4], A1[4], A2[4], H[4];
      #pragma unroll
      for (int q = 0; q < 4; ++q) {
        A0[q] = o1r[q*64 + lane];
        A1[q] = o2r[q*128 + lane];
        A2[q] = o2r[q*128 + 64 + lane];
        H[q] = bb;
      }
      #pragma unroll 4
      for (int c = 0; c < 64; ++c) {
        const float wv = sw[c*64 + lane];
        #pragma unroll
        for (int q = 0; q < 4; ++q) H[q] = fmaf(__shfl(A0[q], c, 64), wv, H[q]);
      }
      #pragma unroll 4
      for (int c = 0; c < 64; ++c) {
        const float wv = sw[(64 + c)*64 + lane];
        #pragma unroll
        for (int q = 0; q < 4; ++q) H[q] = fmaf(__shfl(A1[q], c, 64), wv, H[q]);
      }
      #pragma unroll 4
      for (int c = 0; c < 64; ++c) {
        const float wv = sw[(128 + c)*64 + lane];
        #pragma unroll
        for (int q = 0; q < 4; ++q) H[q] = fmaf(__shfl(A2[q], c, 64), wv, H[q]);
      }
      #pragma unroll
      for (int q = 0; q < 4; ++q) acc += fmaxf(H[q], 0.f);
    }
    atomicAdd(&pool[b*512 + ct*64 + lane], acc);
  }
}

// ---------------- head: mean -> 512 -> 256 -> 10 ----------------------------
__global__ __launch_bounds__(256) void head_kernel(
    const float* __restrict__ pool,
    const float* __restrict__ w1, const float* __restrict__ b1,
    const float* __restrict__ w2, const float* __restrict__ b2,
    const float* __restrict__ w3, const float* __restrict__ b3,
    float* __restrict__ out)
{
  __shared__ float g0[512], g1[512], g2[256];
  const int b = blockIdx.x, t = threadIdx.x;
  for (int k = t; k < 512; k += 256) g0[k] = pool[b*512 + k] * (1.0f/2048.0f);
  __syncthreads();
  for (int o = t; o < 512; o += 256) {
    float s = b1[o];
    for (int c = 0; c < 512; ++c) s = fmaf(g0[c], w1[(size_t)c*512 + o], s);
    g1[o] = fmaxf(s, 0.f);
  }
  __syncthreads();
  {
    const int o = t;
    if (o < 256) {
      float s = b2[o];
      for (int c = 0; c < 512; ++c) s = fmaf(g1[c], w2[(size_t)c*256 + o], s);
      g2[o] = fmaxf(s, 0.f);
    }
  }
  __syncthreads();
  if (t < 10) {
    float s = b3[t];
    for (int c = 0; c < 256; ++c) s = fmaf(g2[c], w3[c*10 + t], s);
    out[b*10 + t] = s;
  }
}

extern "C" void kernel_launch(void* const* d_in, const int* in_sizes, int n_in,
                              void* d_out, int out_size, void* d_ws, size_t ws_size,
                              hipStream_t stream) {
  const float* pos  = (const float*)d_in[0];
  const float* c1w1 = (const float*)d_in[1];
  const float* c1b1 = (const float*)d_in[2];
  const float* c1w2 = (const float*)d_in[3];
  const float* c1b2 = (const float*)d_in[4];
  const float* c2w1 = (const float*)d_in[5];
  const float* c2b1 = (const float*)d_in[6];
  const float* m1w1 = (const float*)d_in[7];
  const float* m1b1 = (const float*)d_in[8];
  const float* m2w1 = (const float*)d_in[9];
  const float* m2b1 = (const float*)d_in[10];
  const float* m2w2 = (const float*)d_in[11];
  const float* m2b2 = (const float*)d_in[12];
  const float* m2w3 = (const float*)d_in[13];
  const float* m2b3 = (const float*)d_in[14];

  float* out1 = (float*)d_ws;                        // 16*2048*64
  float* out2 = out1 + (size_t)NB*NP*64;             // 16*2048*128
  float* nrm  = out2 + (size_t)NB*NP*128;            // 16*2048
  int*   knn  = (int*)(nrm + (size_t)NB*NP);         // 16*2048*20
  float* pool = (float*)(knn + (size_t)NB*NP*KNN);   // 16*512

  hipMemsetAsync(pool, 0, NB*512*sizeof(float), stream);
  ec1_kernel<<<dim3(NB, 64), 256, 0, stream>>>(pos, c1w1, c1b1, c1w2, c1b2, out1);
  norms_kernel<<<dim3(NB*NP/256), 256, 0, stream>>>(out1, nrm);
  ec2knn_kernel<<<dim3(NB, 256), 256, 0, stream>>>(out1, nrm, knn);
  ec2mlp_kernel<<<dim3(NB, 64), 256, 0, stream>>>(out1, knn, c2w1, c2b1, out2);
  m1pool_kernel<<<dim3(NB, 32), 256, 0, stream>>>(out1, out2, m1w1, m1b1, pool);
  head_kernel<<<dim3(NB), 256, 0, stream>>>(pool, m2w1, m2b1, m2w2, m2b2, m2w3, m2b3,
                                            (float*)d_out);
}

// Round 2
// 1847.602 us; speedup vs baseline: 1.5486x; 1.5486x over previous
//
#include <hip/hip_runtime.h>

#define NB 16
#define NP 2048
#define KNN 20
#define INFD 3.0e38f

// broadcast lane l's value to all lanes; with compile-time l -> v_readlane imm (no lgkm)
__device__ __forceinline__ float bcast(float v, int l) {
  return __int_as_float(__builtin_amdgcn_readlane(__float_as_int(v), l));
}

// wave-wide argmin on (d, j), tie -> smaller j. All lanes end with the winner.
__device__ __forceinline__ void wave_argmin(float& d, int& j) {
  #pragma unroll
  for (int m = 1; m < 64; m <<= 1) {
    const float pd = __shfl_xor(d, m, 64);
    const int   pj = __shfl_xor(j, m, 64);
    if (pd < d || (pd == d && pj < j)) { d = pd; j = pj; }
  }
}

// top-20 of 2048 candidates, d[tt] is dist of candidate j = tt*64+lane.
// Threshold T = max over 32 lane-pairs of pair-min guarantees >=32 entries <= T,
// so the top-20 are all in the compacted pool. Exact fallback if pool overflows.
// Writes dst[0..19] (global or LDS) from lane 0, in selection order.
__device__ __forceinline__ void topk20(float (&d)[32], const int lane,
                                       float* __restrict__ cd, int* __restrict__ cj,
                                       int* __restrict__ dst)
{
  float bd = d[0];
  #pragma unroll
  for (int tt = 1; tt < 32; ++tt) bd = fminf(bd, d[tt]);
  float t = fminf(bd, __shfl_xor(bd, 1, 64));
  #pragma unroll
  for (int m = 2; m < 64; m <<= 1) t = fmaxf(t, __shfl_xor(t, m, 64));

  #pragma unroll
  for (int s = 0; s < 4; ++s) { cd[s*64 + lane] = INFD; cj[s*64 + lane] = 0x7fffffff; }
  int base = 0;
  #pragma unroll
  for (int tt = 0; tt < 32; ++tt) {
    const bool p = (d[tt] <= t);
    const unsigned long long mask = __ballot(p);
    if (p) {
      const int off = base + (int)__popcll(mask & ((1ull << lane) - 1ull));
      if (off < 256) { cd[off] = d[tt]; cj[off] = tt*64 + lane; }
    }
    base += (int)__popcll(mask);
  }
  if (base <= 256) {
    float ed[4]; int ej[4];
    #pragma unroll
    for (int s = 0; s < 4; ++s) { ed[s] = cd[s*64 + lane]; ej[s] = cj[s*64 + lane]; }
    #pragma unroll 1
    for (int n = 0; n < KNN; ++n) {
      float md = ed[0]; int mj = ej[0];
      #pragma unroll
      for (int s = 1; s < 4; ++s)          // slot order is ascending j: strict < keeps smaller j
        if (ed[s] < md) { md = ed[s]; mj = ej[s]; }
      wave_argmin(md, mj);
      if (lane == 0) dst[n] = mj;
      #pragma unroll
      for (int s = 0; s < 4; ++s)
        if (ej[s] == mj) ed[s] = INFD;
    }
  } else {
    // exact slow path (rare): extract directly from d[32]
    #pragma unroll 1
    for (int n = 0; n < KNN; ++n) {
      float md = INFD; int mj = 0x7fffffff;
      #pragma unroll
      for (int tt = 0; tt < 32; ++tt)
        if (d[tt] < md) { md = d[tt]; mj = tt*64 + lane; }
      wave_argmin(md, mj);
      if (lane == 0) dst[n] = mj;
      #pragma unroll
      for (int tt = 0; tt < 32; ++tt)
        if (tt*64 + lane == mj) d[tt] = INFD;
    }
  }
}

// ---------------- EdgeConv1: 3-dim kNN + MLP(6->64->64) + max + fused norm ----
__global__ __launch_bounds__(256) void ec1_kernel(
    const float* __restrict__ pos, const float* __restrict__ w1,
    const float* __restrict__ b1, const float* __restrict__ w2,
    const float* __restrict__ b2, float* __restrict__ out1,
    float* __restrict__ nrm)
{
  __shared__ float px[NP], py[NP], pz[NP];
  __shared__ float sw1[6*64], sw2[64*64], sb1[64], sb2[64];
  __shared__ float cdb[4][256];
  __shared__ int   cjb[4][256];
  __shared__ int   sidx[4][20];
  const int b = blockIdx.x, tid = threadIdx.x;
  const int wave = tid >> 6, lane = tid & 63;
  const float* pb = pos + (size_t)b * NP * 3;
  for (int k = tid; k < NP; k += 256) {
    px[k] = pb[3*k]; py[k] = pb[3*k+1]; pz[k] = pb[3*k+2];
  }
  for (int k = tid; k < 6*64; k += 256) sw1[k] = w1[k];
  for (int k = tid; k < 64*64; k += 256) sw2[k] = w2[k];
  if (tid < 64) { sb1[tid] = b1[tid]; sb2[tid] = b2[tid]; }
  __syncthreads();

  #pragma unroll 1
  for (int p = 0; p < 8; ++p) {
    const int i = blockIdx.y * 32 + wave * 8 + p;
    const float xix = px[i], xiy = py[i], xiz = pz[i];
    const float ni = xix*xix + xiy*xiy + xiz*xiz;
    float d[32];
    #pragma unroll
    for (int tt = 0; tt < 32; ++tt) {
      const int j = tt*64 + lane;
      const float ax = px[j], ay = py[j], az = pz[j];
      const float nj = ax*ax + ay*ay + az*az;
      const float dot = xix*ax + xiy*ay + xiz*az;
      d[tt] = ni + nj - 2.0f*dot;
    }
    topk20(d, lane, cdb[wave], cjb[wave], sidx[wave]);

    float omax = 0.0f;  // post-relu outputs are >= 0
    #pragma unroll 1
    for (int half = 0; half < 2; ++half) {
      float h1[10], a[10];
      #pragma unroll
      for (int u = 0; u < 10; ++u) {
        const int j = sidx[wave][half*10 + u];
        const float xjx = px[j], xjy = py[j], xjz = pz[j];
        float h = sb1[lane];
        h = fmaf(xix, sw1[0*64+lane], h);
        h = fmaf(xiy, sw1[1*64+lane], h);
        h = fmaf(xiz, sw1[2*64+lane], h);
        h = fmaf(xjx - xix, sw1[3*64+lane], h);
        h = fmaf(xjy - xiy, sw1[4*64+lane], h);
        h = fmaf(xjz - xiz, sw1[5*64+lane], h);
        h1[u] = fmaxf(h, 0.0f);
        a[u] = sb2[lane];
      }
      #pragma unroll
      for (int c = 0; c < 64; ++c) {
        const float wv = sw2[c*64 + lane];
        #pragma unroll
        for (int u = 0; u < 10; ++u)
          a[u] = fmaf(bcast(h1[u], c), wv, a[u]);
      }
      #pragma unroll
      for (int u = 0; u < 10; ++u) omax = fmaxf(omax, fmaxf(a[u], 0.0f));
    }
    out1[((size_t)b*NP + i)*64 + lane] = omax;

    float s = omax * omax;                 // fused row sq-norm (tree order)
    #pragma unroll
    for (int m = 1; m < 64; m <<= 1) s += __shfl_xor(s, m, 64);
    if (lane == 0) nrm[b*NP + i] = s;
  }
}

// ---------------- EdgeConv2 kNN: 64-dim dists + top-20 ----------------------
__global__ __launch_bounds__(256) void ec2knn_kernel(
    const float* __restrict__ x, const float* __restrict__ nrm, int* __restrict__ knn)
{
  __shared__ float chT[64*129];   // transposed chunk [c][j], pad 129: conflict-free both ways
  __shared__ float snrm[128];
  __shared__ float cdb[4][256];
  __shared__ int   cjb[4][256];
  const int b = blockIdx.x, tid = threadIdx.x;
  const int wave = tid >> 6, lane = tid & 63;
  const int i0 = blockIdx.y*8 + wave*2, i1 = i0 + 1;
  const float* xb = x + (size_t)b * NP * 64;
  const float xi0 = xb[(size_t)i0*64 + lane];
  const float xi1 = xb[(size_t)i1*64 + lane];
  const float ni0 = nrm[b*NP + i0], ni1 = nrm[b*NP + i1];
  float d0[32], d1[32];
  #pragma unroll 1
  for (int ch = 0; ch < 16; ++ch) {
    __syncthreads();
    const float* src = xb + (size_t)ch*128*64;
    #pragma unroll
    for (int q = 0; q < 32; ++q) {          // each wave stages 32 rows, transposing
      const int j = wave*32 + q;
      chT[lane*129 + j] = src[j*64 + lane];
    }
    if (tid < 128) snrm[tid] = nrm[b*NP + ch*128 + tid];
    __syncthreads();
    float a00 = 0.f, a01 = 0.f, a10 = 0.f, a11 = 0.f;
    #pragma unroll
    for (int c = 0; c < 64; ++c) {
      const float xj0 = chT[c*129 + lane];
      const float xj1 = chT[c*129 + 64 + lane];
      const float x0 = bcast(xi0, c);
      const float x1 = bcast(xi1, c);
      a00 = fmaf(x0, xj0, a00);
      a01 = fmaf(x0, xj1, a01);
      a10 = fmaf(x1, xj0, a10);
      a11 = fmaf(x1, xj1, a11);
    }
    const float nj0 = snrm[lane], nj1 = snrm[64 + lane];
    d0[2*ch]     = ni0 + nj0 - 2.0f*a00;
    d0[2*ch + 1] = ni0 + nj1 - 2.0f*a01;
    d1[2*ch]     = ni1 + nj0 - 2.0f*a10;
    d1[2*ch + 1] = ni1 + nj1 - 2.0f*a11;
  }
  topk20(d0, lane, cdb[wave], cjb[wave], knn + ((size_t)b*NP + i0)*KNN);
  topk20(d1, lane, cdb[wave], cjb[wave], knn + ((size_t)b*NP + i1)*KNN);
}

// ---------------- base GEMM: out2 <- bias + out1 @ W[0:64,:]  (xi-part) ------
__global__ __launch_bounds__(256) void basegemm_kernel(
    const float* __restrict__ o1, const float* __restrict__ w,
    const float* __restrict__ bias, float* __restrict__ out2)
{
  __shared__ float sw[64*128];
  const int b = blockIdx.x, tid = threadIdx.x;
  const int wave = tid >> 6, lane = tid & 63;
  for (int k = tid; k < 64*128; k += 256) sw[k] = w[k];
  __syncthreads();
  const int i0 = blockIdx.y*32 + wave*8;
  const float bl0 = bias[lane], bl1 = bias[64 + lane];
  float A[8], a0[8], a1[8];
  #pragma unroll
  for (int r = 0; r < 8; ++r) {
    A[r] = o1[((size_t)b*NP + i0 + r)*64 + lane];
    a0[r] = bl0; a1[r] = bl1;
  }
  #pragma unroll
  for (int c = 0; c < 64; ++c) {
    const float w0  = sw[c*128 + lane];
    const float w1v = sw[c*128 + 64 + lane];
    #pragma unroll
    for (int r = 0; r < 8; ++r) {
      const float s = bcast(A[r], c);
      a0[r] = fmaf(s, w0,  a0[r]);
      a1[r] = fmaf(s, w1v, a1[r]);
    }
  }
  #pragma unroll
  for (int r = 0; r < 8; ++r) {
    out2[((size_t)b*NP + i0 + r)*128 + lane]      = a0[r];
    out2[((size_t)b*NP + i0 + r)*128 + 64 + lane] = a1[r];
  }
}

// ---------------- EdgeConv2 MLP neighbor part + max (in-place on out2) ------
__global__ __launch_bounds__(256) void ec2mlp_kernel(
    const float* __restrict__ x, const int* __restrict__ knnIdx,
    const float* __restrict__ w, float* __restrict__ out2)
{
  __shared__ float sw[64*128];   // W rows 64..127 (the xj-xi part)
  const int b = blockIdx.x, tid = threadIdx.x;
  const int wave = tid >> 6, lane = tid & 63;
  for (int k = tid; k < 64*128; k += 256) sw[k] = w[64*128 + k];
  __syncthreads();
  const float* xb = x + (size_t)b * NP * 64;
  #pragma unroll 1
  for (int p = 0; p < 8; ++p) {
    const int i = blockIdx.y*32 + wave*8 + p;
    const float xi = xb[(size_t)i*64 + lane];
    const float base0 = out2[((size_t)b*NP + i)*128 + lane];
    const float base1 = out2[((size_t)b*NP + i)*128 + 64 + lane];
    const int* ip = knnIdx + ((size_t)b*NP + i)*KNN;
    float m0 = 0.f, m1v = 0.f;   // relu via 0-init
    #pragma unroll 1
    for (int half = 0; half < 2; ++half) {
      float dx[10], a0[10], a1[10];
      #pragma unroll
      for (int u = 0; u < 10; ++u) {
        const int j = ip[half*10 + u];
        dx[u] = xb[(size_t)j*64 + lane] - xi;
        a0[u] = base0; a1[u] = base1;
      }
      #pragma unroll
      for (int c = 0; c < 64; ++c) {
        const float w0  = sw[c*128 + lane];
        const float w1v = sw[c*128 + 64 + lane];
        #pragma unroll
        for (int u = 0; u < 10; ++u) {
          const float e = bcast(dx[u], c);
          a0[u] = fmaf(e, w0,  a0[u]);
          a1[u] = fmaf(e, w1v, a1[u]);
        }
      }
      #pragma unroll
      for (int u = 0; u < 10; ++u) {
        m0  = fmaxf(m0,  a0[u]);
        m1v = fmaxf(m1v, a1[u]);
      }
    }
    out2[((size_t)b*NP + i)*128 + lane]      = m0;
    out2[((size_t)b*NP + i)*128 + 64 + lane] = m1v;
  }
}

// ---------------- m1: relu([out1|out2] @ W192x512 + b), mean-pool -----------
__global__ __launch_bounds__(256) void m1pool_kernel(
    const float* __restrict__ o1, const float* __restrict__ o2,
    const float* __restrict__ w, const float* __restrict__ bias,
    float* __restrict__ pool)
{
  __shared__ float sw[192*64];
  const int b = blockIdx.x, tid = threadIdx.x;
  const int wave = tid >> 6, lane = tid & 63;
  const int rbase = blockIdx.y * 64 + wave * 16;
  #pragma unroll 1
  for (int ct = 0; ct < 8; ++ct) {
    __syncthreads();
    for (int k = tid; k < 192*64; k += 256)
      sw[k] = w[(size_t)(k >> 6)*512 + ct*64 + (k & 63)];
    __syncthreads();
    const float bb = bias[ct*64 + lane];
    float acc = 0.f;
    #pragma unroll 1
    for (int g = 0; g < 2; ++g) {
      const int r = rbase + g*8;
      const float* o1r = o1 + ((size_t)b*NP + r)*64;
      const float* o2r = o2 + ((size_t)b*NP + r)*128;
      float A0[8], A1[8], A2[8], H[8];
      #pragma unroll
      for (int q = 0; q < 8; ++q) {
        A0[q] = o1r[q*64 + lane];
        A1[q] = o2r[q*128 + lane];
        A2[q] = o2r[q*128 + 64 + lane];
        H[q] = bb;
      }
      #pragma unroll
      for (int c = 0; c < 64; ++c) {
        const float wv = sw[c*64 + lane];
        #pragma unroll
        for (int q = 0; q < 8; ++q) H[q] = fmaf(bcast(A0[q], c), wv, H[q]);
      }
      #pragma unroll
      for (int c = 0; c < 64; ++c) {
        const float wv = sw[(64 + c)*64 + lane];
        #pragma unroll
        for (int q = 0; q < 8; ++q) H[q] = fmaf(bcast(A1[q], c), wv, H[q]);
      }
      #pragma unroll
      for (int c = 0; c < 64; ++c) {
        const float wv = sw[(128 + c)*64 + lane];
        #pragma unroll
        for (int q = 0; q < 8; ++q) H[q] = fmaf(bcast(A2[q], c), wv, H[q]);
      }
      #pragma unroll
      for (int q = 0; q < 8; ++q) acc += fmaxf(H[q], 0.f);
    }
    atomicAdd(&pool[b*512 + ct*64 + lane], acc);
  }
}

// ---------------- head: mean -> 512 -> 256 -> 10 ----------------------------
__global__ __launch_bounds__(256) void head_kernel(
    const float* __restrict__ pool,
    const float* __restrict__ w1, const float* __restrict__ b1,
    const float* __restrict__ w2, const float* __restrict__ b2,
    const float* __restrict__ w3, const float* __restrict__ b3,
    float* __restrict__ out)
{
  __shared__ float g0[512], g1[512], g2[256];
  const int b = blockIdx.x, t = threadIdx.x;
  for (int k = t; k < 512; k += 256) g0[k] = pool[b*512 + k] * (1.0f/2048.0f);
  __syncthreads();
  for (int o = t; o < 512; o += 256) {
    float s = b1[o];
    for (int c = 0; c < 512; ++c) s = fmaf(g0[c], w1[(size_t)c*512 + o], s);
    g1[o] = fmaxf(s, 0.f);
  }
  __syncthreads();
  if (t < 256) {
    float s = b2[t];
    for (int c = 0; c < 512; ++c) s = fmaf(g1[c], w2[(size_t)c*256 + t], s);
    g2[t] = fmaxf(s, 0.f);
  }
  __syncthreads();
  if (t < 10) {
    float s = b3[t];
    for (int c = 0; c < 256; ++c) s = fmaf(g2[c], w3[c*10 + t], s);
    out[b*10 + t] = s;
  }
}

extern "C" void kernel_launch(void* const* d_in, const int* in_sizes, int n_in,
                              void* d_out, int out_size, void* d_ws, size_t ws_size,
                              hipStream_t stream) {
  const float* pos  = (const float*)d_in[0];
  const float* c1w1 = (const float*)d_in[1];
  const float* c1b1 = (const float*)d_in[2];
  const float* c1w2 = (const float*)d_in[3];
  const float* c1b2 = (const float*)d_in[4];
  const float* c2w1 = (const float*)d_in[5];
  const float* c2b1 = (const float*)d_in[6];
  const float* m1w1 = (const float*)d_in[7];
  const float* m1b1 = (const float*)d_in[8];
  const float* m2w1 = (const float*)d_in[9];
  const float* m2b1 = (const float*)d_in[10];
  const float* m2w2 = (const float*)d_in[11];
  const float* m2b2 = (const float*)d_in[12];
  const float* m2w3 = (const float*)d_in[13];
  const float* m2b3 = (const float*)d_in[14];

  float* out1 = (float*)d_ws;                        // 16*2048*64
  float* out2 = out1 + (size_t)NB*NP*64;             // 16*2048*128
  float* nrm  = out2 + (size_t)NB*NP*128;            // 16*2048
  int*   knn  = (int*)(nrm + (size_t)NB*NP);         // 16*2048*20
  float* pool = (float*)(knn + (size_t)NB*NP*KNN);   // 16*512

  hipMemsetAsync(pool, 0, NB*512*sizeof(float), stream);
  ec1_kernel<<<dim3(NB, 64), 256, 0, stream>>>(pos, c1w1, c1b1, c1w2, c1b2, out1, nrm);
  ec2knn_kernel<<<dim3(NB, 256), 256, 0, stream>>>(out1, nrm, knn);
  basegemm_kernel<<<dim3(NB, 64), 256, 0, stream>>>(out1, c2w1, c2b1, out2);
  ec2mlp_kernel<<<dim3(NB, 64), 256, 0, stream>>>(out1, knn, c2w1, out2);
  m1pool_kernel<<<dim3(NB, 32), 256, 0, stream>>>(out1, out2, m1w1, m1b1, pool);
  head_kernel<<<dim3(NB), 256, 0, stream>>>(pool, m2w1, m2b1, m2w2, m2b2, m2w3, m2b3,
                                            (float*)d_out);
}

// Round 4
// 1449.801 us; speedup vs baseline: 1.9735x; 1.2744x over previous
//
#include <hip/hip_runtime.h>

#define NB 16
#define NP 2048
#define KNN 20
#define INFD 3.0e38f

// monotonic float->uint key (handles tiny negative dists from fp cancellation)
__device__ __forceinline__ unsigned fkey(float f) {
  unsigned u = __float_as_uint(f);
  return (u & 0x80000000u) ? ~u : (u | 0x80000000u);
}

// broadcast lane l's value to all lanes; compile-time l -> v_readlane imm
__device__ __forceinline__ float bcast(float v, int l) {
  return __int_as_float(__builtin_amdgcn_readlane(__float_as_int(v), l));
}

// exact fallback only (pool overflow, ~never)
__device__ __forceinline__ void wave_argmin(float& d, int& j) {
  #pragma unroll
  for (int m = 1; m < 64; m <<= 1) {
    const float pd = __shfl_xor(d, m, 64);
    const int   pj = __shfl_xor(j, m, 64);
    if (pd < d || (pd == d && pj < j)) { d = pd; j = pj; }
  }
}

// top-20 of 2048 candidates; d[tt] is dist of candidate j = tt*64+lane.
// Threshold T (max over 32 lane-pair-group mins) guarantees >=32 entries <= T.
// Pool holds packed keys (fkey(d)<<32)|j in ascending-j order (keys unique).
// Rank of each entry = #keys strictly smaller -> ranks 0..n-1; top-20 = rank<20.
// dst[rank] = j. No dependent cross-lane chains anywhere in the hot path.
__device__ __forceinline__ void topk20(float (&d)[32], const int lane,
                                       unsigned long long* __restrict__ pool,
                                       int* __restrict__ dst)
{
  float bd = d[0];
  #pragma unroll
  for (int tt = 1; tt < 32; ++tt) bd = fminf(bd, d[tt]);
  float t = fminf(bd, __shfl_xor(bd, 1, 64));
  #pragma unroll
  for (int m = 2; m < 64; m <<= 1) t = fmaxf(t, __shfl_xor(t, m, 64));

  int base = 0;
  #pragma unroll
  for (int tt = 0; tt < 32; ++tt) {
    const bool p = (d[tt] <= t);
    const unsigned long long mask = __ballot(p);
    if (p) {
      const int off = base + (int)__popcll(mask & ((1ull << lane) - 1ull));
      if (off < 256)
        pool[off] = ((unsigned long long)fkey(d[tt]) << 32) | (unsigned)(tt*64 + lane);
    }
    base += (int)__popcll(mask);
  }

  if (base <= 256) {
    const int n = base;                      // wave-uniform
    if (lane == 0 && (n & 1)) pool[n] = ~0ull;   // pad for paired loads (pool sized 260)
    asm volatile("s_waitcnt lgkmcnt(0)" ::: "memory");  // wave-level LDS visibility
    __builtin_amdgcn_sched_barrier(0);
    unsigned long long mykey[4]; int cnt[4];
    #pragma unroll
    for (int s = 0; s < 4; ++s) { mykey[s] = pool[s*64 + lane]; cnt[s] = 0; }
    const int nn = (n + 1) & ~1;
    #pragma unroll 2
    for (int e = 0; e < nn; e += 2) {
      const unsigned long long k0 = pool[e];
      const unsigned long long k1 = pool[e + 1];
      #pragma unroll
      for (int s = 0; s < 4; ++s) {
        cnt[s] += (k0 < mykey[s]) ? 1 : 0;
        cnt[s] += (k1 < mykey[s]) ? 1 : 0;
      }
    }
    #pragma unroll
    for (int s = 0; s < 4; ++s) {
      const int idx = s*64 + lane;
      if (idx < n && cnt[s] < KNN)
        dst[cnt[s]] = (int)(mykey[s] & 0xffffffffu);
    }
  } else {
    // exact slow path (rare): extract directly from d[32]
    #pragma unroll 1
    for (int nsel = 0; nsel < KNN; ++nsel) {
      float md = INFD; int mj = 0x7fffffff;
      #pragma unroll
      for (int tt = 0; tt < 32; ++tt)
        if (d[tt] < md) { md = d[tt]; mj = tt*64 + lane; }
      wave_argmin(md, mj);
      if (lane == 0) dst[nsel] = mj;
      #pragma unroll
      for (int tt = 0; tt < 32; ++tt)
        if (tt*64 + lane == mj) d[tt] = INFD;
    }
  }
  asm volatile("s_waitcnt lgkmcnt(0)" ::: "memory");  // dst (LDS case) visible to wave
  __builtin_amdgcn_sched_barrier(0);
}

// ---------------- EdgeConv1: 3-dim kNN + MLP(6->64->64) + max + fused norm ----
__global__ __launch_bounds__(256) void ec1_kernel(
    const float* __restrict__ pos, const float* __restrict__ w1,
    const float* __restrict__ b1, const float* __restrict__ w2,
    const float* __restrict__ b2, float* __restrict__ out1,
    float* __restrict__ nrm)
{
  __shared__ float2 pxy[NP];
  __shared__ float  pz[NP];
  __shared__ float sw1[6*64], sw2[64*64], sb1[64], sb2[64];
  __shared__ __align__(16) unsigned long long cpool[4][260];
  __shared__ int sidx[4][20];
  const int b = blockIdx.x, tid = threadIdx.x;
  const int wave = tid >> 6, lane = tid & 63;
  const float* pb = pos + (size_t)b * NP * 3;
  for (int k = tid; k < NP; k += 256) {
    pxy[k] = make_float2(pb[3*k], pb[3*k+1]); pz[k] = pb[3*k+2];
  }
  for (int k = tid; k < 6*64; k += 256) sw1[k] = w1[k];
  for (int k = tid; k < 64*64; k += 256) sw2[k] = w2[k];
  if (tid < 64) { sb1[tid] = b1[tid]; sb2[tid] = b2[tid]; }
  __syncthreads();

  #pragma unroll 1
  for (int p = 0; p < 8; ++p) {
    const int i = blockIdx.y * 32 + wave * 8 + p;
    const float xix = pxy[i].x, xiy = pxy[i].y, xiz = pz[i];
    const float ni = xix*xix + xiy*xiy + xiz*xiz;
    float d[32];
    #pragma unroll
    for (int tt = 0; tt < 32; ++tt) {
      const int j = tt*64 + lane;
      const float2 axy = pxy[j];
      const float ax = axy.x, ay = axy.y, az = pz[j];
      const float nj = ax*ax + ay*ay + az*az;
      const float dot = xix*ax + xiy*ay + xiz*az;
      d[tt] = ni + nj - 2.0f*dot;
    }
    topk20(d, lane, cpool[wave], sidx[wave]);

    float omax = 0.0f;  // post-relu outputs are >= 0
    #pragma unroll 1
    for (int half = 0; half < 2; ++half) {
      float h1[10], a[10];
      #pragma unroll
      for (int u = 0; u < 10; ++u) {
        const int j = sidx[wave][half*10 + u];
        const float xjx = pxy[j].x, xjy = pxy[j].y, xjz = pz[j];
        float h = sb1[lane];
        h = fmaf(xix, sw1[0*64+lane], h);
        h = fmaf(xiy, sw1[1*64+lane], h);
        h = fmaf(xiz, sw1[2*64+lane], h);
        h = fmaf(xjx - xix, sw1[3*64+lane], h);
        h = fmaf(xjy - xiy, sw1[4*64+lane], h);
        h = fmaf(xjz - xiz, sw1[5*64+lane], h);
        h1[u] = fmaxf(h, 0.0f);
        a[u] = sb2[lane];
      }
      #pragma unroll
      for (int c = 0; c < 64; ++c) {
        const float wv = sw2[c*64 + lane];
        #pragma unroll
        for (int u = 0; u < 10; ++u)
          a[u] = fmaf(bcast(h1[u], c), wv, a[u]);
      }
      #pragma unroll
      for (int u = 0; u < 10; ++u) omax = fmaxf(omax, fmaxf(a[u], 0.0f));
    }
    out1[((size_t)b*NP + i)*64 + lane] = omax;

    float s = omax * omax;                 // fused row sq-norm (tree order)
    #pragma unroll
    for (int m = 1; m < 64; m <<= 1) s += __shfl_xor(s, m, 64);
    if (lane == 0) nrm[b*NP + i] = s;
  }
}

// ---------------- EdgeConv2 kNN: 64-dim dists + top-20 ----------------------
__global__ __launch_bounds__(256) void ec2knn_kernel(
    const float* __restrict__ x, const float* __restrict__ nrm, int* __restrict__ knn)
{
  __shared__ float chT[64*129];   // transposed chunk [c][j], pad 129
  __shared__ float snrm[128];
  __shared__ __align__(16) unsigned long long cpool[4][260];
  const int b = blockIdx.x, tid = threadIdx.x;
  const int wave = tid >> 6, lane = tid & 63;
  const int i0 = blockIdx.y*8 + wave*2, i1 = i0 + 1;
  const float* xb = x + (size_t)b * NP * 64;
  const float xi0 = xb[(size_t)i0*64 + lane];
  const float xi1 = xb[(size_t)i1*64 + lane];
  const float ni0 = nrm[b*NP + i0], ni1 = nrm[b*NP + i1];
  float d0[32], d1[32];
  #pragma unroll 1
  for (int ch = 0; ch < 16; ++ch) {
    __syncthreads();
    const float* src = xb + (size_t)ch*128*64;
    #pragma unroll
    for (int q = 0; q < 32; ++q) {          // each wave stages 32 rows, transposing
      const int j = wave*32 + q;
      chT[lane*129 + j] = src[j*64 + lane];
    }
    if (tid < 128) snrm[tid] = nrm[b*NP + ch*128 + tid];
    __syncthreads();
    float a00 = 0.f, a01 = 0.f, a10 = 0.f, a11 = 0.f;
    #pragma unroll
    for (int c = 0; c < 64; ++c) {
      const float xj0 = chT[c*129 + lane];
      const float xj1 = chT[c*129 + 64 + lane];
      const float x0 = bcast(xi0, c);
      const float x1 = bcast(xi1, c);
      a00 = fmaf(x0, xj0, a00);
      a01 = fmaf(x0, xj1, a01);
      a10 = fmaf(x1, xj0, a10);
      a11 = fmaf(x1, xj1, a11);
    }
    const float nj0 = snrm[lane], nj1 = snrm[64 + lane];
    d0[2*ch]     = ni0 + nj0 - 2.0f*a00;
    d0[2*ch + 1] = ni0 + nj1 - 2.0f*a01;
    d1[2*ch]     = ni1 + nj0 - 2.0f*a10;
    d1[2*ch + 1] = ni1 + nj1 - 2.0f*a11;
  }
  topk20(d0, lane, cpool[wave], knn + ((size_t)b*NP + i0)*KNN);
  topk20(d1, lane, cpool[wave], knn + ((size_t)b*NP + i1)*KNN);
}

// ---------------- base GEMM: out2 <- bias + out1 @ W[0:64,:]  (xi-part) ------
__global__ __launch_bounds__(256) void basegemm_kernel(
    const float* __restrict__ o1, const float* __restrict__ w,
    const float* __restrict__ bias, float* __restrict__ out2)
{
  __shared__ float sw[64*128];
  const int b = blockIdx.x, tid = threadIdx.x;
  const int wave = tid >> 6, lane = tid & 63;
  for (int k = tid; k < 64*128; k += 256) sw[k] = w[k];
  __syncthreads();
  const int i0 = blockIdx.y*32 + wave*8;
  const float bl0 = bias[lane], bl1 = bias[64 + lane];
  float A[8], a0[8], a1[8];
  #pragma unroll
  for (int r = 0; r < 8; ++r) {
    A[r] = o1[((size_t)b*NP + i0 + r)*64 + lane];
    a0[r] = bl0; a1[r] = bl1;
  }
  #pragma unroll
  for (int c = 0; c < 64; ++c) {
    const float w0  = sw[c*128 + lane];
    const float w1v = sw[c*128 + 64 + lane];
    #pragma unroll
    for (int r = 0; r < 8; ++r) {
      const float s = bcast(A[r], c);
      a0[r] = fmaf(s, w0,  a0[r]);
      a1[r] = fmaf(s, w1v, a1[r]);
    }
  }
  #pragma unroll
  for (int r = 0; r < 8; ++r) {
    out2[((size_t)b*NP + i0 + r)*128 + lane]      = a0[r];
    out2[((size_t)b*NP + i0 + r)*128 + 64 + lane] = a1[r];
  }
}

// ---------------- EdgeConv2 MLP neighbor part + max (in-place on out2) ------
__global__ __launch_bounds__(256) void ec2mlp_kernel(
    const float* __restrict__ x, const int* __restrict__ knnIdx,
    const float* __restrict__ w, float* __restrict__ out2)
{
  __shared__ float sw[64*128];   // W rows 64..127 (the xj-xi part)
  const int b = blockIdx.x, tid = threadIdx.x;
  const int wave = tid >> 6, lane = tid & 63;
  for (int k = tid; k < 64*128; k += 256) sw[k] = w[64*128 + k];
  __syncthreads();
  const float* xb = x + (size_t)b * NP * 64;
  #pragma unroll 1
  for (int p = 0; p < 8; ++p) {
    const int i = blockIdx.y*32 + wave*8 + p;
    const float xi = xb[(size_t)i*64 + lane];
    const float base0 = out2[((size_t)b*NP + i)*128 + lane];
    const float base1 = out2[((size_t)b*NP + i)*128 + 64 + lane];
    const int* ip = knnIdx + ((size_t)b*NP + i)*KNN;
    float m0 = 0.f, m1v = 0.f;   // relu via 0-init
    #pragma unroll 1
    for (int half = 0; half < 2; ++half) {
      float dx[10], a0[10], a1[10];
      #pragma unroll
      for (int u = 0; u < 10; ++u) {
        const int j = ip[half*10 + u];
        dx[u] = xb[(size_t)j*64 + lane] - xi;
        a0[u] = base0; a1[u] = base1;
      }
      #pragma unroll
      for (int c = 0; c < 64; ++c) {
        const float w0  = sw[c*128 + lane];
        const float w1v = sw[c*128 + 64 + lane];
        #pragma unroll
        for (int u = 0; u < 10; ++u) {
          const float e = bcast(dx[u], c);
          a0[u] = fmaf(e, w0,  a0[u]);
          a1[u] = fmaf(e, w1v, a1[u]);
        }
      }
      #pragma unroll
      for (int u = 0; u < 10; ++u) {
        m0  = fmaxf(m0,  a0[u]);
        m1v = fmaxf(m1v, a1[u]);
      }
    }
    out2[((size_t)b*NP + i)*128 + lane]      = m0;
    out2[((size_t)b*NP + i)*128 + 64 + lane] = m1v;
  }
}

// ---------------- m1: relu([out1|out2] @ W192x512 + b), mean-pool -----------
__global__ __launch_bounds__(256) void m1pool_kernel(
    const float* __restrict__ o1, const float* __restrict__ o2,
    const float* __restrict__ w, const float* __restrict__ bias,
    float* __restrict__ pool)
{
  __shared__ float sw[192*64];
  const int b = blockIdx.x, tid = threadIdx.x;
  const int wave = tid >> 6, lane = tid & 63;
  const int rbase = blockIdx.y * 64 + wave * 16;
  #pragma unroll 1
  for (int ct = 0; ct < 8; ++ct) {
    __syncthreads();
    for (int k = tid; k < 192*64; k += 256)
      sw[k] = w[(size_t)(k >> 6)*512 + ct*64 + (k & 63)];
    __syncthreads();
    const float bb = bias[ct*64 + lane];
    float acc = 0.f;
    #pragma unroll 1
    for (int g = 0; g < 2; ++g) {
      const int r = rbase + g*8;
      const float* o1r = o1 + ((size_t)b*NP + r)*64;
      const float* o2r = o2 + ((size_t)b*NP + r)*128;
      float A0[8], A1[8], A2[8], H[8];
      #pragma unroll
      for (int q = 0; q < 8; ++q) {
        A0[q] = o1r[q*64 + lane];
        A1[q] = o2r[q*128 + lane];
        A2[q] = o2r[q*128 + 64 + lane];
        H[q] = bb;
      }
      #pragma unroll
      for (int c = 0; c < 64; ++c) {
        const float wv = sw[c*64 + lane];
        #pragma unroll
        for (int q = 0; q < 8; ++q) H[q] = fmaf(bcast(A0[q], c), wv, H[q]);
      }
      #pragma unroll
      for (int c = 0; c < 64; ++c) {
        const float wv = sw[(64 + c)*64 + lane];
        #pragma unroll
        for (int q = 0; q < 8; ++q) H[q] = fmaf(bcast(A1[q], c), wv, H[q]);
      }
      #pragma unroll
      for (int c = 0; c < 64; ++c) {
        const float wv = sw[(128 + c)*64 + lane];
        #pragma unroll
        for (int q = 0; q < 8; ++q) H[q] = fmaf(bcast(A2[q], c), wv, H[q]);
      }
      #pragma unroll
      for (int q = 0; q < 8; ++q) acc += fmaxf(H[q], 0.f);
    }
    atomicAdd(&pool[b*512 + ct*64 + lane], acc);
  }
}

// ---------------- head: mean -> 512 -> 256 -> 10 ----------------------------
__global__ __launch_bounds__(256) void head_kernel(
    const float* __restrict__ pool,
    const float* __restrict__ w1, const float* __restrict__ b1,
    const float* __restrict__ w2, const float* __restrict__ b2,
    const float* __restrict__ w3, const float* __restrict__ b3,
    float* __restrict__ out)
{
  __shared__ float g0[512], g1[512], g2[256];
  const int b = blockIdx.x, t = threadIdx.x;
  for (int k = t; k < 512; k += 256) g0[k] = pool[b*512 + k] * (1.0f/2048.0f);
  __syncthreads();
  for (int o = t; o < 512; o += 256) {
    float s = b1[o];
    for (int c = 0; c < 512; ++c) s = fmaf(g0[c], w1[(size_t)c*512 + o], s);
    g1[o] = fmaxf(s, 0.f);
  }
  __syncthreads();
  if (t < 256) {
    float s = b2[t];
    for (int c = 0; c < 512; ++c) s = fmaf(g1[c], w2[(size_t)c*256 + t], s);
    g2[t] = fmaxf(s, 0.f);
  }
  __syncthreads();
  if (t < 10) {
    float s = b3[t];
    for (int c = 0; c < 256; ++c) s = fmaf(g2[c], w3[c*10 + t], s);
    out[b*10 + t] = s;
  }
}

extern "C" void kernel_launch(void* const* d_in, const int* in_sizes, int n_in,
                              void* d_out, int out_size, void* d_ws, size_t ws_size,
                              hipStream_t stream) {
  const float* pos  = (const float*)d_in[0];
  const float* c1w1 = (const float*)d_in[1];
  const float* c1b1 = (const float*)d_in[2];
  const float* c1w2 = (const float*)d_in[3];
  const float* c1b2 = (const float*)d_in[4];
  const float* c2w1 = (const float*)d_in[5];
  const float* c2b1 = (const float*)d_in[6];
  const float* m1w1 = (const float*)d_in[7];
  const float* m1b1 = (const float*)d_in[8];
  const float* m2w1 = (const float*)d_in[9];
  const float* m2b1 = (const float*)d_in[10];
  const float* m2w2 = (const float*)d_in[11];
  const float* m2b2 = (const float*)d_in[12];
  const float* m2w3 = (const float*)d_in[13];
  const float* m2b3 = (const float*)d_in[14];

  float* out1 = (float*)d_ws;                        // 16*2048*64
  float* out2 = out1 + (size_t)NB*NP*64;             // 16*2048*128
  float* nrm  = out2 + (size_t)NB*NP*128;            // 16*2048
  int*   knn  = (int*)(nrm + (size_t)NB*NP);         // 16*2048*20
  float* pool = (float*)(knn + (size_t)NB*NP*KNN);   // 16*512

  hipMemsetAsync(pool, 0, NB*512*sizeof(float), stream);
  ec1_kernel<<<dim3(NB, 64), 256, 0, stream>>>(pos, c1w1, c1b1, c1w2, c1b2, out1, nrm);
  ec2knn_kernel<<<dim3(NB, 256), 256, 0, stream>>>(out1, nrm, knn);
  basegemm_kernel<<<dim3(NB, 64), 256, 0, stream>>>(out1, c2w1, c2b1, out2);
  ec2mlp_kernel<<<dim3(NB, 64), 256, 0, stream>>>(out1, knn, c2w1, out2);
  m1pool_kernel<<<dim3(NB, 32), 256, 0, stream>>>(out1, out2, m1w1, m1b1, pool);
  head_kernel<<<dim3(NB), 256, 0, stream>>>(pool, m2w1, m2b1, m2w2, m2b2, m2w3, m2b3,
                                            (float*)d_out);
}

// Round 5
// 1124.841 us; speedup vs baseline: 2.5436x; 1.2889x over previous
//
#include <hip/hip_runtime.h>

#define NB 16
#define NP 2048
#define KNN 20
#define INFD 3.0e38f

typedef short bf16x8 __attribute__((ext_vector_type(8)));
typedef float f32x16 __attribute__((ext_vector_type(16)));

// monotonic float->uint key (handles tiny negative dists from fp cancellation)
__device__ __forceinline__ unsigned fkey(float f) {
  unsigned u = __float_as_uint(f);
  return (u & 0x80000000u) ? ~u : (u | 0x80000000u);
}

// broadcast lane l's value to all lanes; compile-time l -> v_readlane imm
__device__ __forceinline__ float bcast(float v, int l) {
  return __int_as_float(__builtin_amdgcn_readlane(__float_as_int(v), l));
}

// fp32 -> bf16 RNE on raw bits (finite inputs)
__device__ __forceinline__ unsigned short f2bf(float f) {
  unsigned u = __float_as_uint(f);
  return (unsigned short)((u + 0x7fffu + ((u >> 16) & 1u)) >> 16);
}
// split x ~= hi + lo (each bf16); residual ~2^-16 * |x|
__device__ __forceinline__ void bfsplit(float f, unsigned short& h, unsigned short& l) {
  h = f2bf(f);
  l = f2bf(f - __uint_as_float((unsigned)h << 16));
}

// exact fallback only (pool overflow, ~never)
__device__ __forceinline__ void wave_argmin(float& d, int& j) {
  #pragma unroll
  for (int m = 1; m < 64; m <<= 1) {
    const float pd = __shfl_xor(d, m, 64);
    const int   pj = __shfl_xor(j, m, 64);
    if (pd < d || (pd == d && pj < j)) { d = pd; j = pj; }
  }
}

// top-20 of 2048 candidates; d[tt] is dist of candidate j = tt*64+lane.
// Threshold T (max over 32 lane-pair-group mins) guarantees >=32 entries <= T.
// Rank-based selection: rank = #keys strictly smaller; dst[rank] = j for rank<20.
__device__ __forceinline__ void topk20(float (&d)[32], const int lane,
                                       unsigned long long* __restrict__ pool,
                                       int* __restrict__ dst)
{
  float bd = d[0];
  #pragma unroll
  for (int tt = 1; tt < 32; ++tt) bd = fminf(bd, d[tt]);
  float t = fminf(bd, __shfl_xor(bd, 1, 64));
  #pragma unroll
  for (int m = 2; m < 64; m <<= 1) t = fmaxf(t, __shfl_xor(t, m, 64));

  int base = 0;
  #pragma unroll
  for (int tt = 0; tt < 32; ++tt) {
    const bool p = (d[tt] <= t);
    const unsigned long long mask = __ballot(p);
    if (p) {
      const int off = base + (int)__popcll(mask & ((1ull << lane) - 1ull));
      if (off < 256)
        pool[off] = ((unsigned long long)fkey(d[tt]) << 32) | (unsigned)(tt*64 + lane);
    }
    base += (int)__popcll(mask);
  }

  if (base <= 256) {
    const int n = base;                      // wave-uniform
    if (lane == 0) { pool[n] = ~0ull; pool[n+1] = ~0ull; pool[n+2] = ~0ull; } // pads (pool[260+3])
    asm volatile("s_waitcnt lgkmcnt(0)" ::: "memory");
    __builtin_amdgcn_sched_barrier(0);
    unsigned long long mykey[4]; int cnt[4];
    #pragma unroll
    for (int s = 0; s < 4; ++s) { mykey[s] = pool[s*64 + lane]; cnt[s] = 0; }
    const int nn4 = (n + 3) & ~3;
    #pragma unroll 2
    for (int e = 0; e < nn4; e += 4) {      // 2x ds_read_b128, uniform addr (broadcast)
      const ulonglong2 kA = *(const ulonglong2*)(pool + e);
      const ulonglong2 kB = *(const ulonglong2*)(pool + e + 2);
      #pragma unroll
      for (int s = 0; s < 4; ++s) {
        cnt[s] += (kA.x < mykey[s]) ? 1 : 0;
        cnt[s] += (kA.y < mykey[s]) ? 1 : 0;
        cnt[s] += (kB.x < mykey[s]) ? 1 : 0;
        cnt[s] += (kB.y < mykey[s]) ? 1 : 0;
      }
    }
    #pragma unroll
    for (int s = 0; s < 4; ++s) {
      const int idx = s*64 + lane;
      if (idx < n && cnt[s] < KNN)
        dst[cnt[s]] = (int)(mykey[s] & 0xffffffffu);
    }
  } else {
    #pragma unroll 1
    for (int nsel = 0; nsel < KNN; ++nsel) {
      float md = INFD; int mj = 0x7fffffff;
      #pragma unroll
      for (int tt = 0; tt < 32; ++tt)
        if (d[tt] < md) { md = d[tt]; mj = tt*64 + lane; }
      wave_argmin(md, mj);
      if (lane == 0) dst[nsel] = mj;
      #pragma unroll
      for (int tt = 0; tt < 32; ++tt)
        if (tt*64 + lane == mj) d[tt] = INFD;
    }
  }
  asm volatile("s_waitcnt lgkmcnt(0)" ::: "memory");
  __builtin_amdgcn_sched_barrier(0);
}

// ---------------- EdgeConv1: 3-dim kNN + MLP(6->64->64) + max + fused norm ----
// fp32 exact: out1 feeds EC2's kNN selection, must stay bit-stable.
__global__ __launch_bounds__(256) void ec1_kernel(
    const float* __restrict__ pos, const float* __restrict__ w1,
    const float* __restrict__ b1, const float* __restrict__ w2,
    const float* __restrict__ b2, float* __restrict__ out1,
    float* __restrict__ nrm)
{
  __shared__ float2 pxy[NP];
  __shared__ float  pz[NP];
  __shared__ float sw1[6*64], sw2[64*64], sb1[64], sb2[64];
  __shared__ __align__(16) unsigned long long cpool[4][264];
  __shared__ int sidx[4][20];
  const int b = blockIdx.x, tid = threadIdx.x;
  const int wave = tid >> 6, lane = tid & 63;
  const float* pb = pos + (size_t)b * NP * 3;
  for (int k = tid; k < NP; k += 256) {
    pxy[k] = make_float2(pb[3*k], pb[3*k+1]); pz[k] = pb[3*k+2];
  }
  for (int k = tid; k < 6*64; k += 256) sw1[k] = w1[k];
  for (int k = tid; k < 64*64; k += 256) sw2[k] = w2[k];
  if (tid < 64) { sb1[tid] = b1[tid]; sb2[tid] = b2[tid]; }
  __syncthreads();

  #pragma unroll 1
  for (int p = 0; p < 8; ++p) {
    const int i = blockIdx.y * 32 + wave * 8 + p;
    const float xix = pxy[i].x, xiy = pxy[i].y, xiz = pz[i];
    const float ni = xix*xix + xiy*xiy + xiz*xiz;
    float d[32];
    #pragma unroll
    for (int tt = 0; tt < 32; ++tt) {
      const int j = tt*64 + lane;
      const float2 axy = pxy[j];
      const float ax = axy.x, ay = axy.y, az = pz[j];
      const float nj = ax*ax + ay*ay + az*az;
      const float dot = xix*ax + xiy*ay + xiz*az;
      d[tt] = ni + nj - 2.0f*dot;
    }
    topk20(d, lane, cpool[wave], sidx[wave]);

    float omax = 0.0f;  // post-relu outputs are >= 0
    #pragma unroll 1
    for (int half = 0; half < 2; ++half) {
      float h1[10], a[10];
      #pragma unroll
      for (int u = 0; u < 10; ++u) {
        const int j = sidx[wave][half*10 + u];
        const float xjx = pxy[j].x, xjy = pxy[j].y, xjz = pz[j];
        float h = sb1[lane];
        h = fmaf(xix, sw1[0*64+lane], h);
        h = fmaf(xiy, sw1[1*64+lane], h);
        h = fmaf(xiz, sw1[2*64+lane], h);
        h = fmaf(xjx - xix, sw1[3*64+lane], h);
        h = fmaf(xjy - xiy, sw1[4*64+lane], h);
        h = fmaf(xjz - xiz, sw1[5*64+lane], h);
        h1[u] = fmaxf(h, 0.0f);
        a[u] = sb2[lane];
      }
      #pragma unroll
      for (int c = 0; c < 64; ++c) {
        const float wv = sw2[c*64 + lane];
        #pragma unroll
        for (int u = 0; u < 10; ++u)
          a[u] = fmaf(bcast(h1[u], c), wv, a[u]);
      }
      #pragma unroll
      for (int u = 0; u < 10; ++u) omax = fmaxf(omax, fmaxf(a[u], 0.0f));
    }
    out1[((size_t)b*NP + i)*64 + lane] = omax;

    float s = omax * omax;                 // fused row sq-norm (tree order)
    #pragma unroll
    for (int m = 1; m < 64; m <<= 1) s += __shfl_xor(s, m, 64);
    if (lane == 0) nrm[b*NP + i] = s;
  }
}

// ---------------- EdgeConv2 kNN: 64-dim dists + top-20 (fp32 exact) ---------
__global__ __launch_bounds__(256) void ec2knn_kernel(
    const float* __restrict__ x, const float* __restrict__ nrm, int* __restrict__ knn)
{
  __shared__ float chT[64*129];   // transposed chunk [c][j], pad 129
  __shared__ float snrm[128];
  __shared__ __align__(16) unsigned long long cpool[4][264];
  const int b = blockIdx.x, tid = threadIdx.x;
  const int wave = tid >> 6, lane = tid & 63;
  const int i0 = blockIdx.y*8 + wave*2, i1 = i0 + 1;
  const float* xb = x + (size_t)b * NP * 64;
  const float xi0 = xb[(size_t)i0*64 + lane];
  const float xi1 = xb[(size_t)i1*64 + lane];
  const float ni0 = nrm[b*NP + i0], ni1 = nrm[b*NP + i1];
  float d0[32], d1[32];
  #pragma unroll 1
  for (int ch = 0; ch < 16; ++ch) {
    __syncthreads();
    const float* src = xb + (size_t)ch*128*64;
    #pragma unroll
    for (int q = 0; q < 32; ++q) {
      const int j = wave*32 + q;
      chT[lane*129 + j] = src[j*64 + lane];
    }
    if (tid < 128) snrm[tid] = nrm[b*NP + ch*128 + tid];
    __syncthreads();
    float a00 = 0.f, a01 = 0.f, a10 = 0.f, a11 = 0.f;
    #pragma unroll
    for (int c = 0; c < 64; ++c) {
      const float xj0 = chT[c*129 + lane];
      const float xj1 = chT[c*129 + 64 + lane];
      const float x0 = bcast(xi0, c);
      const float x1 = bcast(xi1, c);
      a00 = fmaf(x0, xj0, a00);
      a01 = fmaf(x0, xj1, a01);
      a10 = fmaf(x1, xj0, a10);
      a11 = fmaf(x1, xj1, a11);
    }
    const float nj0 = snrm[lane], nj1 = snrm[64 + lane];
    d0[2*ch]     = ni0 + nj0 - 2.0f*a00;
    d0[2*ch + 1] = ni0 + nj1 - 2.0f*a01;
    d1[2*ch]     = ni1 + nj0 - 2.0f*a10;
    d1[2*ch + 1] = ni1 + nj1 - 2.0f*a11;
  }
  topk20(d0, lane, cpool[wave], knn + ((size_t)b*NP + i0)*KNN);
  topk20(d1, lane, cpool[wave], knn + ((size_t)b*NP + i1)*KNN);
}

// ---------------- base GEMM: out2 <- bias + out1 @ W[0:64,:]  (xi-part) ------
__global__ __launch_bounds__(256) void basegemm_kernel(
    const float* __restrict__ o1, const float* __restrict__ w,
    const float* __restrict__ bias, float* __restrict__ out2)
{
  __shared__ float sw[64*128];
  const int b = blockIdx.x, tid = threadIdx.x;
  const int wave = tid >> 6, lane = tid & 63;
  for (int k = tid; k < 64*128; k += 256) sw[k] = w[k];
  __syncthreads();
  const int i0 = blockIdx.y*32 + wave*8;
  const float bl0 = bias[lane], bl1 = bias[64 + lane];
  float A[8], a0[8], a1[8];
  #pragma unroll
  for (int r = 0; r < 8; ++r) {
    A[r] = o1[((size_t)b*NP + i0 + r)*64 + lane];
    a0[r] = bl0; a1[r] = bl1;
  }
  #pragma unroll
  for (int c = 0; c < 64; ++c) {
    const float w0  = sw[c*128 + lane];
    const float w1v = sw[c*128 + 64 + lane];
    #pragma unroll
    for (int r = 0; r < 8; ++r) {
      const float s = bcast(A[r], c);
      a0[r] = fmaf(s, w0,  a0[r]);
      a1[r] = fmaf(s, w1v, a1[r]);
    }
  }
  #pragma unroll
  for (int r = 0; r < 8; ++r) {
    out2[((size_t)b*NP + i0 + r)*128 + lane]      = a0[r];
    out2[((size_t)b*NP + i0 + r)*128 + 64 + lane] = a1[r];
  }
}

// ------- EdgeConv2 MLP neighbor part, split-bf16 MFMA, in-place on out2 -----
// Per point: 32 edge-rows (20 real + 12 dup of edge 0 -> max unchanged).
// C tile 32x32: col=lane&31, row=(reg&3)+8*(reg>>2)+4*(lane>>5)  [verified map]
// A frag: row=lane&31, k=(lane>>5)*8+idx ; B frag: col=lane&31, k=(lane>>5)*8+idx
__global__ __launch_bounds__(256) void ec2mlp_kernel(
    const float* __restrict__ x, const int* __restrict__ knnIdx,
    const float* __restrict__ w, float* __restrict__ out2)
{
  __shared__ bf16x8 Bf[2][4][4][64];   // [pass][nt][ks][lane] 32 KB
  const int b = blockIdx.x, tid = threadIdx.x;
  const int wave = tid >> 6, lane = tid & 63;
  for (int s = tid; s < 2048; s += 256) {
    const int pass = s >> 10, nt = (s >> 8) & 3, ks = (s >> 6) & 3, l = s & 63;
    bf16x8 v;
    #pragma unroll
    for (int idx = 0; idx < 8; ++idx) {
      const int k = ks*16 + ((l >> 5) << 3) + idx;
      const float wv = w[(size_t)(64 + k)*128 + nt*32 + (l & 31)];
      unsigned short hb, lb; bfsplit(wv, hb, lb);
      v[idx] = (short)(pass ? lb : hb);
    }
    Bf[pass][nt][ks][l] = v;
  }
  __syncthreads();
  const float* xb = x + (size_t)b * NP * 64;
  #pragma unroll 1
  for (int p = 0; p < 8; ++p) {
    const int i = blockIdx.y*32 + wave*8 + p;
    const int e = lane & 31;
    const int* ip = knnIdx + ((size_t)b*NP + i)*KNN;
    const int j = ip[e < KNN ? e : 0];
    const float* xj = xb + (size_t)j*64 + ((lane >> 5) << 3);
    const float* xi = xb + (size_t)i*64 + ((lane >> 5) << 3);
    f32x16 C[4];
    #pragma unroll
    for (int nt = 0; nt < 4; ++nt)
      #pragma unroll
      for (int r = 0; r < 16; ++r) C[nt][r] = 0.f;
    #pragma unroll
    for (int ks = 0; ks < 4; ++ks) {
      const float4 j0 = *(const float4*)(xj + ks*16);
      const float4 j1 = *(const float4*)(xj + ks*16 + 4);
      const float4 i0 = *(const float4*)(xi + ks*16);
      const float4 i1 = *(const float4*)(xi + ks*16 + 4);
      const float dx[8] = { j0.x-i0.x, j0.y-i0.y, j0.z-i0.z, j0.w-i0.w,
                            j1.x-i1.x, j1.y-i1.y, j1.z-i1.z, j1.w-i1.w };
      bf16x8 Ah, Al;
      #pragma unroll
      for (int q = 0; q < 8; ++q) {
        unsigned short hb, lb; bfsplit(dx[q], hb, lb);
        Ah[q] = (short)hb; Al[q] = (short)lb;
      }
      #pragma unroll
      for (int nt = 0; nt < 4; ++nt) {
        const bf16x8 bh = Bf[0][nt][ks][lane];
        const bf16x8 bl = Bf[1][nt][ks][lane];
        C[nt] = __builtin_amdgcn_mfma_f32_32x32x16_bf16(Ah, bh, C[nt], 0, 0, 0);
        C[nt] = __builtin_amdgcn_mfma_f32_32x32x16_bf16(Al, bh, C[nt], 0, 0, 0);
        C[nt] = __builtin_amdgcn_mfma_f32_32x32x16_bf16(Ah, bl, C[nt], 0, 0, 0);
      }
    }
    #pragma unroll
    for (int nt = 0; nt < 4; ++nt) {
      float mx = C[nt][0];
      #pragma unroll
      for (int r = 1; r < 16; ++r) mx = fmaxf(mx, C[nt][r]);
      mx = fmaxf(mx, __shfl_xor(mx, 32, 64));      // other 16 rows live in lane^32
      const float basev = out2[((size_t)b*NP + i)*128 + nt*32 + (lane & 31)];
      const float res = fmaxf(mx + basev, 0.f);    // base const per col: max then add
      if (lane < 32) out2[((size_t)b*NP + i)*128 + nt*32 + lane] = res;
    }
  }
}

// ------- m1+pool: relu([out1|out2] @ W192x512 + b) row-summed, split-bf16 MFMA
__global__ __launch_bounds__(256) void m1pool_kernel(
    const float* __restrict__ o1, const float* __restrict__ o2,
    const float* __restrict__ w, const float* __restrict__ bias,
    float* __restrict__ pool)
{
  __shared__ bf16x8 Bf[2][2][12][64];  // [pass][nt][ks][lane] 48 KB
  const int b = blockIdx.x, tid = threadIdx.x;
  const int wave = tid >> 6, lane = tid & 63;
  const int colbase = blockIdx.y * 64;
  for (int s = tid; s < 3072; s += 256) {
    const int pass = s / 1536;
    const int r1 = s - pass*1536;
    const int nt = r1 / 768;
    const int r2 = r1 - nt*768;
    const int ks = r2 >> 6, l = r2 & 63;
    bf16x8 v;
    #pragma unroll
    for (int idx = 0; idx < 8; ++idx) {
      const int k = ks*16 + ((l >> 5) << 3) + idx;
      const float wv = w[(size_t)k*512 + colbase + nt*32 + (l & 31)];
      unsigned short hb, lb; bfsplit(wv, hb, lb);
      v[idx] = (short)(pass ? lb : hb);
    }
    Bf[pass][nt][ks][l] = v;
  }
  __syncthreads();
  const float bad0 = bias[colbase + (lane & 31)];
  const float bad1 = bias[colbase + 32 + (lane & 31)];
  float acc0 = 0.f, acc1 = 0.f;
  #pragma unroll 1
  for (int rt = 0; rt < 8; ++rt) {
    const int tile = blockIdx.z*32 + wave*8 + rt;        // 64 tiles of 32 rows
    const int row = tile*32 + (lane & 31);
    const float* a1 = o1 + ((size_t)b*NP + row)*64  + ((lane >> 5) << 3);
    const float* a2 = o2 + ((size_t)b*NP + row)*128 + ((lane >> 5) << 3);
    f32x16 C0, C1;
    #pragma unroll
    for (int r = 0; r < 16; ++r) { C0[r] = 0.f; C1[r] = 0.f; }
    #pragma unroll
    for (int ks = 0; ks < 12; ++ks) {
      const float* src = (ks < 4) ? (a1 + ks*16) : (a2 + (ks - 4)*16);
      const float4 v0 = *(const float4*)(src);
      const float4 v1 = *(const float4*)(src + 4);
      const float av[8] = { v0.x, v0.y, v0.z, v0.w, v1.x, v1.y, v1.z, v1.w };
      bf16x8 Ah, Al;
      #pragma unroll
      for (int q = 0; q < 8; ++q) {
        unsigned short hb, lb; bfsplit(av[q], hb, lb);
        Ah[q] = (short)hb; Al[q] = (short)lb;
      }
      {
        const bf16x8 bh = Bf[0][0][ks][lane];
        const bf16x8 bl = Bf[1][0][ks][lane];
        C0 = __builtin_amdgcn_mfma_f32_32x32x16_bf16(Ah, bh, C0, 0, 0, 0);
        C0 = __builtin_amdgcn_mfma_f32_32x32x16_bf16(Al, bh, C0, 0, 0, 0);
        C0 = __builtin_amdgcn_mfma_f32_32x32x16_bf16(Ah, bl, C0, 0, 0, 0);
      }
      {
        const bf16x8 bh = Bf[0][1][ks][lane];
        const bf16x8 bl = Bf[1][1][ks][lane];
        C1 = __builtin_amdgcn_mfma_f32_32x32x16_bf16(Ah, bh, C1, 0, 0, 0);
        C1 = __builtin_amdgcn_mfma_f32_32x32x16_bf16(Al, bh, C1, 0, 0, 0);
        C1 = __builtin_amdgcn_mfma_f32_32x32x16_bf16(Ah, bl, C1, 0, 0, 0);
      }
    }
    float s0 = 0.f, s1 = 0.f;
    #pragma unroll
    for (int r = 0; r < 16; ++r) {
      s0 += fmaxf(C0[r] + bad0, 0.f);
      s1 += fmaxf(C1[r] + bad1, 0.f);
    }
    acc0 += s0 + __shfl_xor(s0, 32, 64);
    acc1 += s1 + __shfl_xor(s1, 32, 64);
  }
  if (lane < 32) {
    atomicAdd(&pool[b*512 + colbase + lane], acc0);
    atomicAdd(&pool[b*512 + colbase + 32 + lane], acc1);
  }
}

// ---------------- head: mean -> 512 -> 256 -> 10 (fp32, tiny) ---------------
__global__ __launch_bounds__(256) void head_kernel(
    const float* __restrict__ pool,
    const float* __restrict__ w1, const float* __restrict__ b1,
    const float* __restrict__ w2, const float* __restrict__ b2,
    const float* __restrict__ w3, const float* __restrict__ b3,
    float* __restrict__ out)
{
  __shared__ float g0[512], g1[512], g2[256];
  const int b = blockIdx.x, t = threadIdx.x;
  for (int k = t; k < 512; k += 256) g0[k] = pool[b*512 + k] * (1.0f/2048.0f);
  __syncthreads();
  for (int o = t; o < 512; o += 256) {
    float s = b1[o];
    for (int c = 0; c < 512; ++c) s = fmaf(g0[c], w1[(size_t)c*512 + o], s);
    g1[o] = fmaxf(s, 0.f);
  }
  __syncthreads();
  if (t < 256) {
    float s = b2[t];
    for (int c = 0; c < 512; ++c) s = fmaf(g1[c], w2[(size_t)c*256 + t], s);
    g2[t] = fmaxf(s, 0.f);
  }
  __syncthreads();
  if (t < 10) {
    float s = b3[t];
    for (int c = 0; c < 256; ++c) s = fmaf(g2[c], w3[c*10 + t], s);
    out[b*10 + t] = s;
  }
}

extern "C" void kernel_launch(void* const* d_in, const int* in_sizes, int n_in,
                              void* d_out, int out_size, void* d_ws, size_t ws_size,
                              hipStream_t stream) {
  const float* pos  = (const float*)d_in[0];
  const float* c1w1 = (const float*)d_in[1];
  const float* c1b1 = (const float*)d_in[2];
  const float* c1w2 = (const float*)d_in[3];
  const float* c1b2 = (const float*)d_in[4];
  const float* c2w1 = (const float*)d_in[5];
  const float* c2b1 = (const float*)d_in[6];
  const float* m1w1 = (const float*)d_in[7];
  const float* m1b1 = (const float*)d_in[8];
  const float* m2w1 = (const float*)d_in[9];
  const float* m2b1 = (const float*)d_in[10];
  const float* m2w2 = (const float*)d_in[11];
  const float* m2b2 = (const float*)d_in[12];
  const float* m2w3 = (const float*)d_in[13];
  const float* m2b3 = (const float*)d_in[14];

  float* out1 = (float*)d_ws;                        // 16*2048*64
  float* out2 = out1 + (size_t)NB*NP*64;             // 16*2048*128
  float* nrm  = out2 + (size_t)NB*NP*128;            // 16*2048
  int*   knn  = (int*)(nrm + (size_t)NB*NP);         // 16*2048*20
  float* pool = (float*)(knn + (size_t)NB*NP*KNN);   // 16*512

  hipMemsetAsync(pool, 0, NB*512*sizeof(float), stream);
  ec1_kernel<<<dim3(NB, 64), 256, 0, stream>>>(pos, c1w1, c1b1, c1w2, c1b2, out1, nrm);
  ec2knn_kernel<<<dim3(NB, 256), 256, 0, stream>>>(out1, nrm, knn);
  basegemm_kernel<<<dim3(NB, 64), 256, 0, stream>>>(out1, c2w1, c2b1, out2);
  ec2mlp_kernel<<<dim3(NB, 64), 256, 0, stream>>>(out1, knn, c2w1, out2);
  m1pool_kernel<<<dim3(NB, 8, 2), 256, 0, stream>>>(out1, out2, m1w1, m1b1, pool);
  head_kernel<<<dim3(NB), 256, 0, stream>>>(pool, m2w1, m2b1, m2w2, m2b2, m2w3, m2b3,
                                            (float*)d_out);
}

// Round 6
// 923.058 us; speedup vs baseline: 3.0997x; 1.2186x over previous
//
#include <hip/hip_runtime.h>

#define NB 16
#define NP 2048
#define KNN 20
#define INFD 3.0e38f

typedef short bf16x8 __attribute__((ext_vector_type(8)));
typedef float f32x16 __attribute__((ext_vector_type(16)));

// monotonic float->uint key (handles tiny negative dists from fp cancellation)
__device__ __forceinline__ unsigned fkey(float f) {
  unsigned u = __float_as_uint(f);
  return (u & 0x80000000u) ? ~u : (u | 0x80000000u);
}

// broadcast lane l's value to all lanes; compile-time l -> v_readlane imm
__device__ __forceinline__ float bcast(float v, int l) {
  return __int_as_float(__builtin_amdgcn_readlane(__float_as_int(v), l));
}

// fp32 -> bf16 RNE on raw bits (finite inputs)
__device__ __forceinline__ unsigned short f2bf(float f) {
  unsigned u = __float_as_uint(f);
  return (unsigned short)((u + 0x7fffu + ((u >> 16) & 1u)) >> 16);
}
// split x ~= hi + lo (each bf16); residual ~2^-16 * |x|
__device__ __forceinline__ void bfsplit(float f, unsigned short& h, unsigned short& l) {
  h = f2bf(f);
  l = f2bf(f - __uint_as_float((unsigned)h << 16));
}

// exact fallback only (pool overflow, ~never)
__device__ __forceinline__ void wave_argmin(float& d, int& j) {
  #pragma unroll
  for (int m = 1; m < 64; m <<= 1) {
    const float pd = __shfl_xor(d, m, 64);
    const int   pj = __shfl_xor(j, m, 64);
    if (pd < d || (pd == d && pj < j)) { d = pd; j = pj; }
  }
}

// top-20 of 2048 candidates; d[tt] is dist of candidate j = tt*64+lane.
// Threshold T (max over 32 lane-pair-group mins) guarantees >=32 entries <= T.
// Rank-based selection: rank = #keys strictly smaller; dst[rank] = j for rank<20.
__device__ __forceinline__ void topk20(float (&d)[32], const int lane,
                                       unsigned long long* __restrict__ pool,
                                       int* __restrict__ dst)
{
  float bd = d[0];
  #pragma unroll
  for (int tt = 1; tt < 32; ++tt) bd = fminf(bd, d[tt]);
  float t = fminf(bd, __shfl_xor(bd, 1, 64));
  #pragma unroll
  for (int m = 2; m < 64; m <<= 1) t = fmaxf(t, __shfl_xor(t, m, 64));

  int base = 0;
  #pragma unroll
  for (int tt = 0; tt < 32; ++tt) {
    const bool p = (d[tt] <= t);
    const unsigned long long mask = __ballot(p);
    if (p) {
      const int off = base + (int)__popcll(mask & ((1ull << lane) - 1ull));
      if (off < 256)
        pool[off] = ((unsigned long long)fkey(d[tt]) << 32) | (unsigned)(tt*64 + lane);
    }
    base += (int)__popcll(mask);
  }

  if (base <= 256) {
    const int n = base;                      // wave-uniform
    if (lane == 0) { pool[n] = ~0ull; pool[n+1] = ~0ull; pool[n+2] = ~0ull; }
    asm volatile("s_waitcnt lgkmcnt(0)" ::: "memory");
    __builtin_amdgcn_sched_barrier(0);
    unsigned long long mykey[4]; int cnt[4];
    #pragma unroll
    for (int s = 0; s < 4; ++s) { mykey[s] = pool[s*64 + lane]; cnt[s] = 0; }
    const int nn4 = (n + 3) & ~3;
    #pragma unroll 2
    for (int e = 0; e < nn4; e += 4) {
      const ulonglong2 kA = *(const ulonglong2*)(pool + e);
      const ulonglong2 kB = *(const ulonglong2*)(pool + e + 2);
      #pragma unroll
      for (int s = 0; s < 4; ++s) {
        cnt[s] += (kA.x < mykey[s]) ? 1 : 0;
        cnt[s] += (kA.y < mykey[s]) ? 1 : 0;
        cnt[s] += (kB.x < mykey[s]) ? 1 : 0;
        cnt[s] += (kB.y < mykey[s]) ? 1 : 0;
      }
    }
    #pragma unroll
    for (int s = 0; s < 4; ++s) {
      const int idx = s*64 + lane;
      if (idx < n && cnt[s] < KNN)
        dst[cnt[s]] = (int)(mykey[s] & 0xffffffffu);
    }
  } else {
    #pragma unroll 1
    for (int nsel = 0; nsel < KNN; ++nsel) {
      float md = INFD; int mj = 0x7fffffff;
      #pragma unroll
      for (int tt = 0; tt < 32; ++tt)
        if (d[tt] < md) { md = d[tt]; mj = tt*64 + lane; }
      wave_argmin(md, mj);
      if (lane == 0) dst[nsel] = mj;
      #pragma unroll
      for (int tt = 0; tt < 32; ++tt)
        if (tt*64 + lane == mj) d[tt] = INFD;
    }
  }
  asm volatile("s_waitcnt lgkmcnt(0)" ::: "memory");
  __builtin_amdgcn_sched_barrier(0);
}

// ---- EdgeConv1: exact 3-dim kNN + MLP(6->64 VALU, 64->64 split-bf16 MFMA) ----
__global__ __launch_bounds__(256) void ec1_kernel(
    const float* __restrict__ pos, const float* __restrict__ w1,
    const float* __restrict__ b1, const float* __restrict__ w2,
    const float* __restrict__ b2, float* __restrict__ out1,
    float* __restrict__ nrm)
{
  __shared__ float2 pxy[NP];
  __shared__ float  pz[NP];
  // per-wave scratch: topk pool (2112 B) and packed-h1 transpose (5120 B), disjoint phases
  __shared__ __align__(16) unsigned scratch[4][1280];
  __shared__ int sidx[4][20];
  const int b = blockIdx.x, tid = threadIdx.x;
  const int wave = tid >> 6, lane = tid & 63;
  const int hi = lane >> 5, cl = lane & 31;
  const float* pb = pos + (size_t)b * NP * 3;
  for (int k = tid; k < NP; k += 256) {
    pxy[k] = make_float2(pb[3*k], pb[3*k+1]); pz[k] = pb[3*k+2];
  }
  // W1 row cache (lane = h1 channel)
  const float w10 = w1[0*64+lane], w11 = w1[1*64+lane], w12 = w1[2*64+lane];
  const float w13 = w1[3*64+lane], w14 = w1[4*64+lane], w15 = w1[5*64+lane];
  const float b1l = b1[lane];
  const float b2c0 = b2[cl], b2c1 = b2[32 + cl];
  // W2 B-fragments in registers (verified convention: col=l&31, k=ks*16+hi*8+idx)
  bf16x8 W2h[2][4], W2l[2][4];
  #pragma unroll
  for (int nt = 0; nt < 2; ++nt)
    #pragma unroll
    for (int ks = 0; ks < 4; ++ks)
      #pragma unroll
      for (int idx = 0; idx < 8; ++idx) {
        const int k = ks*16 + hi*8 + idx;
        unsigned short hbv, lbv; bfsplit(w2[k*64 + nt*32 + cl], hbv, lbv);
        W2h[nt][ks][idx] = (short)hbv; W2l[nt][ks][idx] = (short)lbv;
      }
  __syncthreads();
  unsigned long long* pool = (unsigned long long*)scratch[wave];
  unsigned* sh1 = scratch[wave];

  #pragma unroll 1
  for (int p = 0; p < 8; ++p) {
    const int i = blockIdx.y * 32 + wave * 8 + p;
    const float xix = pxy[i].x, xiy = pxy[i].y, xiz = pz[i];
    const float ni = xix*xix + xiy*xiy + xiz*xiz;
    float d[32];
    #pragma unroll
    for (int tt = 0; tt < 32; ++tt) {
      const int j = tt*64 + lane;
      const float2 axy = pxy[j];
      const float ax = axy.x, ay = axy.y, az = pz[j];
      const float nj = ax*ax + ay*ay + az*az;
      const float dot = xix*ax + xiy*ay + xiz*az;
      d[tt] = ni + nj - 2.0f*dot;
    }
    topk20(d, lane, pool, sidx[wave]);

    // h1 stage: lane = channel; write packed (hi|lo) bf16 to swizzled LDS transpose
    const int jreg = sidx[wave][cl < 20 ? cl : 0];
    const float hbase = fmaf(xiz, w12, fmaf(xiy, w11, fmaf(xix, w10, b1l)));
    #pragma unroll
    for (int u = 0; u < 20; ++u) {
      const int j = __builtin_amdgcn_readlane(jreg, u);
      const float2 axy = pxy[j]; const float az = pz[j];
      float h = fmaf(az - xiz, w15, fmaf(axy.y - xiy, w14, fmaf(axy.x - xix, w13, hbase)));
      h = fmaxf(h, 0.0f);
      unsigned short hbv, lbv; bfsplit(h, hbv, lbv);
      sh1[u*64 + (lane ^ ((u & 15) << 1))] = (unsigned)hbv | ((unsigned)lbv << 16);
    }
    asm volatile("s_waitcnt lgkmcnt(0)" ::: "memory");
    __builtin_amdgcn_sched_barrier(0);

    // MFMA: A row = edge (lanes 20..31 dup edge 0 -> max unchanged)
    const int ee = cl < 20 ? cl : 0;
    const int ebase = ee*64, esw = (ee & 15) << 1;
    f32x16 C0, C1;
    #pragma unroll
    for (int r = 0; r < 16; ++r) { C0[r] = 0.f; C1[r] = 0.f; }
    #pragma unroll
    for (int ks = 0; ks < 4; ++ks) {
      const int k8 = ks*16 + hi*8;
      const uint2 P0 = *(const uint2*)(sh1 + ebase + ((k8+0)^esw));
      const uint2 P1 = *(const uint2*)(sh1 + ebase + ((k8+2)^esw));
      const uint2 P2 = *(const uint2*)(sh1 + ebase + ((k8+4)^esw));
      const uint2 P3 = *(const uint2*)(sh1 + ebase + ((k8+6)^esw));
      union { bf16x8 v; unsigned u[4]; } Ah, Al;
      Ah.u[0] = (P0.x & 0xffffu) | (P0.y << 16);  Al.u[0] = (P0.x >> 16) | (P0.y & 0xffff0000u);
      Ah.u[1] = (P1.x & 0xffffu) | (P1.y << 16);  Al.u[1] = (P1.x >> 16) | (P1.y & 0xffff0000u);
      Ah.u[2] = (P2.x & 0xffffu) | (P2.y << 16);  Al.u[2] = (P2.x >> 16) | (P2.y & 0xffff0000u);
      Ah.u[3] = (P3.x & 0xffffu) | (P3.y << 16);  Al.u[3] = (P3.x >> 16) | (P3.y & 0xffff0000u);
      C0 = __builtin_amdgcn_mfma_f32_32x32x16_bf16(Ah.v, W2h[0][ks], C0, 0, 0, 0);
      C0 = __builtin_amdgcn_mfma_f32_32x32x16_bf16(Al.v, W2h[0][ks], C0, 0, 0, 0);
      C0 = __builtin_amdgcn_mfma_f32_32x32x16_bf16(Ah.v, W2l[0][ks], C0, 0, 0, 0);
      C1 = __builtin_amdgcn_mfma_f32_32x32x16_bf16(Ah.v, W2h[1][ks], C1, 0, 0, 0);
      C1 = __builtin_amdgcn_mfma_f32_32x32x16_bf16(Al.v, W2h[1][ks], C1, 0, 0, 0);
      C1 = __builtin_amdgcn_mfma_f32_32x32x16_bf16(Ah.v, W2l[1][ks], C1, 0, 0, 0);
    }
    float m0 = C0[0], m1v = C1[0];
    #pragma unroll
    for (int r = 1; r < 16; ++r) { m0 = fmaxf(m0, C0[r]); m1v = fmaxf(m1v, C1[r]); }
    m0  = fmaxf(m0,  __shfl_xor(m0, 32, 64));
    m1v = fmaxf(m1v, __shfl_xor(m1v, 32, 64));
    const float r0 = fmaxf(m0 + b2c0, 0.f);
    const float r1 = fmaxf(m1v + b2c1, 0.f);
    if (lane < 32) {
      out1[((size_t)b*NP + i)*64 + lane]      = r0;
      out1[((size_t)b*NP + i)*64 + 32 + lane] = r1;
    }
    float s = r0*r0 + r1*r1;
    #pragma unroll
    for (int m = 1; m < 32; m <<= 1) s += __shfl_xor(s, m, 64);
    if (lane == 0) nrm[b*NP + i] = s;
  }
}

// ---- EdgeConv2 kNN: split-bf16 MFMA dists + LDS redistribute + top-20 ----
__global__ __launch_bounds__(256) void ec2knn_kernel(
    const float* __restrict__ out1, const float* __restrict__ nrm,
    int* __restrict__ knn)
{
  __shared__ bf16x8 Bf[2][4][4][64];          // [pass][tile][ks][lane] 32 KB
  __shared__ float sdist[16][129];            // stride 129: conflict-spread
  __shared__ float snrm[128];
  __shared__ __align__(16) unsigned long long cpool[4][264];
  const int b = blockIdx.x, tid = threadIdx.x;
  const int wave = tid >> 6, lane = tid & 63;
  const int hi = lane >> 5, cl = lane & 31;
  const int pbase = blockIdx.y * 16;
  const float* xb = out1 + (size_t)b * NP * 64;
  // A fragments: 16 real rows dup'd to 32
  const int arow = pbase + (cl & 15);
  const float* ap = xb + (size_t)arow*64 + hi*8;
  bf16x8 Ahf[4], Alf[4];
  #pragma unroll
  for (int ks = 0; ks < 4; ++ks) {
    const float4 v0 = *(const float4*)(ap + ks*16);
    const float4 v1 = *(const float4*)(ap + ks*16 + 4);
    const float av[8] = {v0.x, v0.y, v0.z, v0.w, v1.x, v1.y, v1.z, v1.w};
    #pragma unroll
    for (int q = 0; q < 8; ++q) {
      unsigned short hbv, lbv; bfsplit(av[q], hbv, lbv);
      Ahf[ks][q] = (short)hbv; Alf[ks][q] = (short)lbv;
    }
  }
  const int p0 = pbase + wave*4;
  const float ni0 = nrm[b*NP + p0];
  const float ni1 = nrm[b*NP + p0 + 1];
  const float ni2 = nrm[b*NP + p0 + 2];
  const float ni3 = nrm[b*NP + p0 + 3];
  float d0[32], d1[32], d2[32], d3[32];
  #pragma unroll
  for (int ch = 0; ch < 16; ++ch) {
    __syncthreads();
    #pragma unroll
    for (int s4 = 0; s4 < 4; ++s4) {
      const int s = s4*256 + tid;
      const int tile = s >> 8, ksx = (s >> 6) & 3, l = s & 63;
      const int cand = ch*128 + tile*32 + (l & 31);
      const int kk = ksx*16 + ((l >> 5) << 3);
      const float* sp = xb + (size_t)cand*64 + kk;
      const float4 v0 = *(const float4*)(sp);
      const float4 v1 = *(const float4*)(sp + 4);
      const float av[8] = {v0.x, v0.y, v0.z, v0.w, v1.x, v1.y, v1.z, v1.w};
      bf16x8 vh, vl;
      #pragma unroll
      for (int q = 0; q < 8; ++q) {
        unsigned short hbv, lbv; bfsplit(av[q], hbv, lbv);
        vh[q] = (short)hbv; vl[q] = (short)lbv;
      }
      Bf[0][tile][ksx][l] = vh; Bf[1][tile][ksx][l] = vl;
    }
    if (tid < 128) snrm[tid] = nrm[b*NP + ch*128 + tid];
    __syncthreads();
    f32x16 C;
    #pragma unroll
    for (int r = 0; r < 16; ++r) C[r] = 0.f;
    #pragma unroll
    for (int ks = 0; ks < 4; ++ks) {
      const bf16x8 bh = Bf[0][wave][ks][lane];
      const bf16x8 bl = Bf[1][wave][ks][lane];
      C = __builtin_amdgcn_mfma_f32_32x32x16_bf16(Ahf[ks], bh, C, 0, 0, 0);
      C = __builtin_amdgcn_mfma_f32_32x32x16_bf16(Alf[ks], bh, C, 0, 0, 0);
      C = __builtin_amdgcn_mfma_f32_32x32x16_bf16(Ahf[ks], bl, C, 0, 0, 0);
    }
    #pragma unroll
    for (int r = 0; r < 8; ++r) {
      const int row = (r & 3) + 8*(r >> 2) + 4*hi;   // rows 0..15
      sdist[row][wave*32 + cl] = C[r];
    }
    __syncthreads();
    const float njA = snrm[lane], njB = snrm[64 + lane];
    d0[2*ch]   = ni0 + njA - 2.f*sdist[wave*4+0][lane];
    d0[2*ch+1] = ni0 + njB - 2.f*sdist[wave*4+0][64+lane];
    d1[2*ch]   = ni1 + njA - 2.f*sdist[wave*4+1][lane];
    d1[2*ch+1] = ni1 + njB - 2.f*sdist[wave*4+1][64+lane];
    d2[2*ch]   = ni2 + njA - 2.f*sdist[wave*4+2][lane];
    d2[2*ch+1] = ni2 + njB - 2.f*sdist[wave*4+2][64+lane];
    d3[2*ch]   = ni3 + njA - 2.f*sdist[wave*4+3][lane];
    d3[2*ch+1] = ni3 + njB - 2.f*sdist[wave*4+3][64+lane];
  }
  topk20(d0, lane, cpool[wave], knn + ((size_t)b*NP + p0 + 0)*KNN);
  topk20(d1, lane, cpool[wave], knn + ((size_t)b*NP + p0 + 1)*KNN);
  topk20(d2, lane, cpool[wave], knn + ((size_t)b*NP + p0 + 2)*KNN);
  topk20(d3, lane, cpool[wave], knn + ((size_t)b*NP + p0 + 3)*KNN);
}

// ---- base GEMM (MFMA): out2 <- bias + out1 @ W[0:64,:] ----
__global__ __launch_bounds__(256) void basegemm_kernel(
    const float* __restrict__ out1, const float* __restrict__ w,
    const float* __restrict__ bias, float* __restrict__ out2)
{
  const int b = blockIdx.x, tid = threadIdx.x;
  const int wave = tid >> 6, lane = tid & 63;
  const int hi = lane >> 5, cl = lane & 31;
  bf16x8 Wh[4], Wl[4];
  #pragma unroll
  for (int ks = 0; ks < 4; ++ks)
    #pragma unroll
    for (int idx = 0; idx < 8; ++idx) {
      const int k = ks*16 + hi*8 + idx;
      unsigned short hbv, lbv; bfsplit(w[(size_t)k*128 + wave*32 + cl], hbv, lbv);
      Wh[ks][idx] = (short)hbv; Wl[ks][idx] = (short)lbv;
    }
  const int row0 = blockIdx.y * 32;
  const float* ap = out1 + ((size_t)b*NP + row0 + cl)*64 + hi*8;
  bf16x8 Ah[4], Al[4];
  #pragma unroll
  for (int ks = 0; ks < 4; ++ks) {
    const float4 v0 = *(const float4*)(ap + ks*16);
    const float4 v1 = *(const float4*)(ap + ks*16 + 4);
    const float av[8] = {v0.x, v0.y, v0.z, v0.w, v1.x, v1.y, v1.z, v1.w};
    #pragma unroll
    for (int q = 0; q < 8; ++q) {
      unsigned short hbv, lbv; bfsplit(av[q], hbv, lbv);
      Ah[ks][q] = (short)hbv; Al[ks][q] = (short)lbv;
    }
  }
  f32x16 C;
  #pragma unroll
  for (int r = 0; r < 16; ++r) C[r] = 0.f;
  #pragma unroll
  for (int ks = 0; ks < 4; ++ks) {
    C = __builtin_amdgcn_mfma_f32_32x32x16_bf16(Ah[ks], Wh[ks], C, 0, 0, 0);
    C = __builtin_amdgcn_mfma_f32_32x32x16_bf16(Al[ks], Wh[ks], C, 0, 0, 0);
    C = __builtin_amdgcn_mfma_f32_32x32x16_bf16(Ah[ks], Wl[ks], C, 0, 0, 0);
  }
  const float bl = bias[wave*32 + cl];
  #pragma unroll
  for (int r = 0; r < 16; ++r) {
    const int row = (r & 3) + 8*(r >> 2) + 4*hi;
    out2[((size_t)b*NP + row0 + row)*128 + wave*32 + cl] = C[r] + bl;
  }
}

// ------- EdgeConv2 MLP neighbor part, split-bf16 MFMA, in-place on out2 -----
__global__ __launch_bounds__(256) void ec2mlp_kernel(
    const float* __restrict__ x, const int* __restrict__ knnIdx,
    const float* __restrict__ w, float* __restrict__ out2)
{
  __shared__ bf16x8 Bf[2][4][4][64];   // [pass][nt][ks][lane] 32 KB
  const int b = blockIdx.x, tid = threadIdx.x;
  const int wave = tid >> 6, lane = tid & 63;
  for (int s = tid; s < 2048; s += 256) {
    const int pass = s >> 10, nt = (s >> 8) & 3, ks = (s >> 6) & 3, l = s & 63;
    bf16x8 v;
    #pragma unroll
    for (int idx = 0; idx < 8; ++idx) {
      const int k = ks*16 + ((l >> 5) << 3) + idx;
      const float wv = w[(size_t)(64 + k)*128 + nt*32 + (l & 31)];
      unsigned short hb, lb; bfsplit(wv, hb, lb);
      v[idx] = (short)(pass ? lb : hb);
    }
    Bf[pass][nt][ks][l] = v;
  }
  __syncthreads();
  const float* xb = x + (size_t)b * NP * 64;
  #pragma unroll 1
  for (int p = 0; p < 8; ++p) {
    const int i = blockIdx.y*32 + wave*8 + p;
    const int e = lane & 31;
    const int* ip = knnIdx + ((size_t)b*NP + i)*KNN;
    const int j = ip[e < KNN ? e : 0];
    const float* xj = xb + (size_t)j*64 + ((lane >> 5) << 3);
    const float* xi = xb + (size_t)i*64 + ((lane >> 5) << 3);
    f32x16 C[4];
    #pragma unroll
    for (int nt = 0; nt < 4; ++nt)
      #pragma unroll
      for (int r = 0; r < 16; ++r) C[nt][r] = 0.f;
    #pragma unroll
    for (int ks = 0; ks < 4; ++ks) {
      const float4 j0 = *(const float4*)(xj + ks*16);
      const float4 j1 = *(const float4*)(xj + ks*16 + 4);
      const float4 i0 = *(const float4*)(xi + ks*16);
      const float4 i1 = *(const float4*)(xi + ks*16 + 4);
      const float dx[8] = { j0.x-i0.x, j0.y-i0.y, j0.z-i0.z, j0.w-i0.w,
                            j1.x-i1.x, j1.y-i1.y, j1.z-i1.z, j1.w-i1.w };
      bf16x8 Ah, Al;
      #pragma unroll
      for (int q = 0; q < 8; ++q) {
        unsigned short hb, lb; bfsplit(dx[q], hb, lb);
        Ah[q] = (short)hb; Al[q] = (short)lb;
      }
      #pragma unroll
      for (int nt = 0; nt < 4; ++nt) {
        const bf16x8 bh = Bf[0][nt][ks][lane];
        const bf16x8 bl = Bf[1][nt][ks][lane];
        C[nt] = __builtin_amdgcn_mfma_f32_32x32x16_bf16(Ah, bh, C[nt], 0, 0, 0);
        C[nt] = __builtin_amdgcn_mfma_f32_32x32x16_bf16(Al, bh, C[nt], 0, 0, 0);
        C[nt] = __builtin_amdgcn_mfma_f32_32x32x16_bf16(Ah, bl, C[nt], 0, 0, 0);
      }
    }
    #pragma unroll
    for (int nt = 0; nt < 4; ++nt) {
      float mx = C[nt][0];
      #pragma unroll
      for (int r = 1; r < 16; ++r) mx = fmaxf(mx, C[nt][r]);
      mx = fmaxf(mx, __shfl_xor(mx, 32, 64));
      const float basev = out2[((size_t)b*NP + i)*128 + nt*32 + (lane & 31)];
      const float res = fmaxf(mx + basev, 0.f);
      if (lane < 32) out2[((size_t)b*NP + i)*128 + nt*32 + lane] = res;
    }
  }
}

// ------- m1+pool: relu([out1|out2] @ W192x512 + b) row-summed, split-bf16 MFMA
__global__ __launch_bounds__(256) void m1pool_kernel(
    const float* __restrict__ o1, const float* __restrict__ o2,
    const float* __restrict__ w, const float* __restrict__ bias,
    float* __restrict__ pool)
{
  __shared__ bf16x8 Bf[2][2][12][64];  // [pass][nt][ks][lane] 48 KB
  const int b = blockIdx.x, tid = threadIdx.x;
  const int wave = tid >> 6, lane = tid & 63;
  const int colbase = blockIdx.y * 64;
  for (int s = tid; s < 3072; s += 256) {
    const int pass = s / 1536;
    const int r1 = s - pass*1536;
    const int nt = r1 / 768;
    const int r2 = r1 - nt*768;
    const int ks = r2 >> 6, l = r2 & 63;
    bf16x8 v;
    #pragma unroll
    for (int idx = 0; idx < 8; ++idx) {
      const int k = ks*16 + ((l >> 5) << 3) + idx;
      const float wv = w[(size_t)k*512 + colbase + nt*32 + (l & 31)];
      unsigned short hb, lb; bfsplit(wv, hb, lb);
      v[idx] = (short)(pass ? lb : hb);
    }
    Bf[pass][nt][ks][l] = v;
  }
  __syncthreads();
  const float bad0 = bias[colbase + (lane & 31)];
  const float bad1 = bias[colbase + 32 + (lane & 31)];
  float acc0 = 0.f, acc1 = 0.f;
  #pragma unroll 1
  for (int rt = 0; rt < 8; ++rt) {
    const int tile = blockIdx.z*32 + wave*8 + rt;
    const int row = tile*32 + (lane & 31);
    const float* a1 = o1 + ((size_t)b*NP + row)*64  + ((lane >> 5) << 3);
    const float* a2 = o2 + ((size_t)b*NP + row)*128 + ((lane >> 5) << 3);
    f32x16 C0, C1;
    #pragma unroll
    for (int r = 0; r < 16; ++r) { C0[r] = 0.f; C1[r] = 0.f; }
    #pragma unroll
    for (int ks = 0; ks < 12; ++ks) {
      const float* src = (ks < 4) ? (a1 + ks*16) : (a2 + (ks - 4)*16);
      const float4 v0 = *(const float4*)(src);
      const float4 v1 = *(const float4*)(src + 4);
      const float av[8] = { v0.x, v0.y, v0.z, v0.w, v1.x, v1.y, v1.z, v1.w };
      bf16x8 Ah, Al;
      #pragma unroll
      for (int q = 0; q < 8; ++q) {
        unsigned short hb, lb; bfsplit(av[q], hb, lb);
        Ah[q] = (short)hb; Al[q] = (short)lb;
      }
      {
        const bf16x8 bh = Bf[0][0][ks][lane];
        const bf16x8 bl = Bf[1][0][ks][lane];
        C0 = __builtin_amdgcn_mfma_f32_32x32x16_bf16(Ah, bh, C0, 0, 0, 0);
        C0 = __builtin_amdgcn_mfma_f32_32x32x16_bf16(Al, bh, C0, 0, 0, 0);
        C0 = __builtin_amdgcn_mfma_f32_32x32x16_bf16(Ah, bl, C0, 0, 0, 0);
      }
      {
        const bf16x8 bh = Bf[0][1][ks][lane];
        const bf16x8 bl = Bf[1][1][ks][lane];
        C1 = __builtin_amdgcn_mfma_f32_32x32x16_bf16(Ah, bh, C1, 0, 0, 0);
        C1 = __builtin_amdgcn_mfma_f32_32x32x16_bf16(Al, bh, C1, 0, 0, 0);
        C1 = __builtin_amdgcn_mfma_f32_32x32x16_bf16(Ah, bl, C1, 0, 0, 0);
      }
    }
    float s0 = 0.f, s1 = 0.f;
    #pragma unroll
    for (int r = 0; r < 16; ++r) {
      s0 += fmaxf(C0[r] + bad0, 0.f);
      s1 += fmaxf(C1[r] + bad1, 0.f);
    }
    acc0 += s0 + __shfl_xor(s0, 32, 64);
    acc1 += s1 + __shfl_xor(s1, 32, 64);
  }
  if (lane < 32) {
    atomicAdd(&pool[b*512 + colbase + lane], acc0);
    atomicAdd(&pool[b*512 + colbase + 32 + lane], acc1);
  }
}

// ---------------- head: mean -> 512 -> 256 -> 10 (fp32, tiny) ---------------
__global__ __launch_bounds__(256) void head_kernel(
    const float* __restrict__ pool,
    const float* __restrict__ w1, const float* __restrict__ b1,
    const float* __restrict__ w2, const float* __restrict__ b2,
    const float* __restrict__ w3, const float* __restrict__ b3,
    float* __restrict__ out)
{
  __shared__ float g0[512], g1[512], g2[256];
  const int b = blockIdx.x, t = threadIdx.x;
  for (int k = t; k < 512; k += 256) g0[k] = pool[b*512 + k] * (1.0f/2048.0f);
  __syncthreads();
  for (int o = t; o < 512; o += 256) {
    float s = b1[o];
    for (int c = 0; c < 512; ++c) s = fmaf(g0[c], w1[(size_t)c*512 + o], s);
    g1[o] = fmaxf(s, 0.f);
  }
  __syncthreads();
  if (t < 256) {
    float s = b2[t];
    for (int c = 0; c < 512; ++c) s = fmaf(g1[c], w2[(size_t)c*256 + t], s);
    g2[t] = fmaxf(s, 0.f);
  }
  __syncthreads();
  if (t < 10) {
    float s = b3[t];
    for (int c = 0; c < 256; ++c) s = fmaf(g2[c], w3[c*10 + t], s);
    out[b*10 + t] = s;
  }
}

extern "C" void kernel_launch(void* const* d_in, const int* in_sizes, int n_in,
                              void* d_out, int out_size, void* d_ws, size_t ws_size,
                              hipStream_t stream) {
  const float* pos  = (const float*)d_in[0];
  const float* c1w1 = (const float*)d_in[1];
  const float* c1b1 = (const float*)d_in[2];
  const float* c1w2 = (const float*)d_in[3];
  const float* c1b2 = (const float*)d_in[4];
  const float* c2w1 = (const float*)d_in[5];
  const float* c2b1 = (const float*)d_in[6];
  const float* m1w1 = (const float*)d_in[7];
  const float* m1b1 = (const float*)d_in[8];
  const float* m2w1 = (const float*)d_in[9];
  const float* m2b1 = (const float*)d_in[10];
  const float* m2w2 = (const float*)d_in[11];
  const float* m2b2 = (const float*)d_in[12];
  const float* m2w3 = (const float*)d_in[13];
  const float* m2b3 = (const float*)d_in[14];

  float* out1 = (float*)d_ws;                        // 16*2048*64
  float* out2 = out1 + (size_t)NB*NP*64;             // 16*2048*128
  float* nrm  = out2 + (size_t)NB*NP*128;            // 16*2048
  int*   knn  = (int*)(nrm + (size_t)NB*NP);         // 16*2048*20
  float* pool = (float*)(knn + (size_t)NB*NP*KNN);   // 16*512

  hipMemsetAsync(pool, 0, NB*512*sizeof(float), stream);
  ec1_kernel<<<dim3(NB, 64), 256, 0, stream>>>(pos, c1w1, c1b1, c1w2, c1b2, out1, nrm);
  ec2knn_kernel<<<dim3(NB, 128), 256, 0, stream>>>(out1, nrm, knn);
  basegemm_kernel<<<dim3(NB, 64), 256, 0, stream>>>(out1, c2w1, c2b1, out2);
  ec2mlp_kernel<<<dim3(NB, 64), 256, 0, stream>>>(out1, knn, c2w1, out2);
  m1pool_kernel<<<dim3(NB, 8, 2), 256, 0, stream>>>(out1, out2, m1w1, m1b1, pool);
  head_kernel<<<dim3(NB), 256, 0, stream>>>(pool, m2w1, m2b1, m2w2, m2b2, m2w3, m2b3,
                                            (float*)d_out);
}

// Round 7
// 780.717 us; speedup vs baseline: 3.6648x; 1.1823x over previous
//
#include <hip/hip_runtime.h>

#define NB 16
#define NP 2048
#define KNN 20
#define INFD 3.0e38f

typedef short bf16x8 __attribute__((ext_vector_type(8)));
typedef float f32x16 __attribute__((ext_vector_type(16)));

// monotonic float->uint key (handles tiny negative dists from fp cancellation)
__device__ __forceinline__ unsigned fkey(float f) {
  unsigned u = __float_as_uint(f);
  return (u & 0x80000000u) ? ~u : (u | 0x80000000u);
}

// fp32 -> bf16 RNE on raw bits (finite inputs)
__device__ __forceinline__ unsigned short f2bf(float f) {
  unsigned u = __float_as_uint(f);
  return (unsigned short)((u + 0x7fffu + ((u >> 16) & 1u)) >> 16);
}
// split x ~= hi + lo (each bf16); residual ~2^-16 * |x|
__device__ __forceinline__ void bfsplit(float f, unsigned short& h, unsigned short& l) {
  h = f2bf(f);
  l = f2bf(f - __uint_as_float((unsigned)h << 16));
}

// exact fallback only (pool overflow, ~never)
__device__ __forceinline__ void wave_argmin(float& d, int& j) {
  #pragma unroll
  for (int m = 1; m < 64; m <<= 1) {
    const float pd = __shfl_xor(d, m, 64);
    const int   pj = __shfl_xor(j, m, 64);
    if (pd < d || (pd == d && pj < j)) { d = pd; j = pj; }
  }
}

// top-20 of 2048 candidates; d[tt] is dist of candidate j = tt*64+lane.
// Threshold T: rank the 64 lane-mins exactly; T = max lane-min with rank<=19.
// >=20 lanes have rank<=19 (ties only add), each contributes a distinct entry
// <= T, so pool (all d<=T) is a downward-closed superset of the top-20.
// E[pool size] ~ 23. Rank-based selection: rank = #keys strictly smaller;
// dst[rank] = j for rank<20. No dependent cross-lane chains in the hot path.
__device__ __forceinline__ void topk20(float (&d)[32], const int lane,
                                       unsigned long long* __restrict__ pool,
                                       float* __restrict__ sbd,
                                       int* __restrict__ dst)
{
  // tree-min of the lane's 32 dists (short dep chain)
  float m16[16];
  #pragma unroll
  for (int t = 0; t < 16; ++t) m16[t] = fminf(d[2*t], d[2*t+1]);
  #pragma unroll
  for (int t = 0; t < 8; ++t) m16[t] = fminf(m16[t], m16[t+8]);
  #pragma unroll
  for (int t = 0; t < 4; ++t) m16[t] = fminf(m16[t], m16[t+4]);
  const float bd = fminf(fminf(m16[0], m16[2]), fminf(m16[1], m16[3]));

  sbd[lane] = bd;
  asm volatile("s_waitcnt lgkmcnt(0)" ::: "memory");
  __builtin_amdgcn_sched_barrier(0);
  int rk = 0;
  #pragma unroll
  for (int e = 0; e < 64; e += 4) {            // broadcast reads
    const float4 v = *(const float4*)(sbd + e);
    rk += (v.x < bd) + (v.y < bd) + (v.z < bd) + (v.w < bd);
  }
  float tb = (rk <= 19) ? bd : -INFD;
  #pragma unroll
  for (int m = 1; m < 64; m <<= 1) tb = fmaxf(tb, __shfl_xor(tb, m, 64));
  const float t = tb;

  int base = 0;
  #pragma unroll
  for (int tt = 0; tt < 32; ++tt) {
    const bool p = (d[tt] <= t);
    const unsigned long long mask = __ballot(p);
    if (p) {
      const int off = base + (int)__popcll(mask & ((1ull << lane) - 1ull));
      if (off < 256)
        pool[off] = ((unsigned long long)fkey(d[tt]) << 32) | (unsigned)(tt*64 + lane);
    }
    base += (int)__popcll(mask);
  }

  if (base <= 256) {
    const int n = base;                        // wave-uniform, >= 20 by construction
    if (lane == 0) { pool[n] = ~0ull; pool[n+1] = ~0ull; pool[n+2] = ~0ull; }
    asm volatile("s_waitcnt lgkmcnt(0)" ::: "memory");
    __builtin_amdgcn_sched_barrier(0);
    const int nn4 = (n + 3) & ~3;
    #pragma unroll 1
    for (int s = 0; s*64 < n; ++s) {           // 1 iteration typical (n ~ 23)
      const unsigned long long mykey = pool[s*64 + lane];
      int cnt = 0;
      #pragma unroll 1
      for (int e = 0; e < nn4; e += 4) {
        const ulonglong2 kA = *(const ulonglong2*)(pool + e);
        const ulonglong2 kB = *(const ulonglong2*)(pool + e + 2);
        cnt += (kA.x < mykey) ? 1 : 0;
        cnt += (kA.y < mykey) ? 1 : 0;
        cnt += (kB.x < mykey) ? 1 : 0;
        cnt += (kB.y < mykey) ? 1 : 0;
      }
      const int idx = s*64 + lane;
      if (idx < n && cnt < KNN)
        dst[cnt] = (int)(mykey & 0xffffffffu);
    }
  } else {
    #pragma unroll 1
    for (int nsel = 0; nsel < KNN; ++nsel) {
      float md = INFD; int mj = 0x7fffffff;
      #pragma unroll
      for (int tt = 0; tt < 32; ++tt)
        if (d[tt] < md) { md = d[tt]; mj = tt*64 + lane; }
      wave_argmin(md, mj);
      if (lane == 0) dst[nsel] = mj;
      #pragma unroll
      for (int tt = 0; tt < 32; ++tt)
        if (tt*64 + lane == mj) d[tt] = INFD;
    }
  }
  asm volatile("s_waitcnt lgkmcnt(0)" ::: "memory");
  __builtin_amdgcn_sched_barrier(0);
}

// ---- EdgeConv1: exact 3-dim kNN + MLP(6->64 VALU, 64->64 split-bf16 MFMA) ----
__global__ __launch_bounds__(256) void ec1_kernel(
    const float* __restrict__ pos, const float* __restrict__ w1,
    const float* __restrict__ b1, const float* __restrict__ w2,
    const float* __restrict__ b2, float* __restrict__ out1,
    float* __restrict__ nrm)
{
  __shared__ float2 pxy[NP];
  __shared__ float  pz[NP];
  // per-wave scratch: topk pool (2136 B @0) + sbd (256 B @4096) + packed-h1 (5120 B, phase-disjoint)
  __shared__ __align__(16) unsigned scratch[4][1280];
  __shared__ int sidx[4][20];
  const int b = blockIdx.x, tid = threadIdx.x;
  const int wave = tid >> 6, lane = tid & 63;
  const int hi = lane >> 5, cl = lane & 31;
  const float* pb = pos + (size_t)b * NP * 3;
  for (int k = tid; k < NP; k += 256) {
    pxy[k] = make_float2(pb[3*k], pb[3*k+1]); pz[k] = pb[3*k+2];
  }
  // W1 row cache (lane = h1 channel)
  const float w10 = w1[0*64+lane], w11 = w1[1*64+lane], w12 = w1[2*64+lane];
  const float w13 = w1[3*64+lane], w14 = w1[4*64+lane], w15 = w1[5*64+lane];
  const float b1l = b1[lane];
  const float b2c0 = b2[cl], b2c1 = b2[32 + cl];
  // W2 B-fragments in registers (verified convention: col=l&31, k=ks*16+hi*8+idx)
  bf16x8 W2h[2][4], W2l[2][4];
  #pragma unroll
  for (int nt = 0; nt < 2; ++nt)
    #pragma unroll
    for (int ks = 0; ks < 4; ++ks)
      #pragma unroll
      for (int idx = 0; idx < 8; ++idx) {
        const int k = ks*16 + hi*8 + idx;
        unsigned short hbv, lbv; bfsplit(w2[k*64 + nt*32 + cl], hbv, lbv);
        W2h[nt][ks][idx] = (short)hbv; W2l[nt][ks][idx] = (short)lbv;
      }
  __syncthreads();
  unsigned long long* pool = (unsigned long long*)scratch[wave];
  float* sbd = (float*)(scratch[wave] + 1024);
  unsigned* sh1 = scratch[wave];

  #pragma unroll 1
  for (int p = 0; p < 8; ++p) {
    const int i = blockIdx.y * 32 + wave * 8 + p;
    const float xix = pxy[i].x, xiy = pxy[i].y, xiz = pz[i];
    const float ni = xix*xix + xiy*xiy + xiz*xiz;
    float d[32];
    #pragma unroll
    for (int tt = 0; tt < 32; ++tt) {
      const int j = tt*64 + lane;
      const float2 axy = pxy[j];
      const float ax = axy.x, ay = axy.y, az = pz[j];
      const float nj = ax*ax + ay*ay + az*az;
      const float dot = xix*ax + xiy*ay + xiz*az;
      d[tt] = ni + nj - 2.0f*dot;
    }
    topk20(d, lane, pool, sbd, sidx[wave]);

    // h1 stage: lane = channel; write packed (hi|lo) bf16 to swizzled LDS transpose
    const int jreg = sidx[wave][cl < 20 ? cl : 0];
    const float hbase = fmaf(xiz, w12, fmaf(xiy, w11, fmaf(xix, w10, b1l)));
    #pragma unroll
    for (int u = 0; u < 20; ++u) {
      const int j = __builtin_amdgcn_readlane(jreg, u);
      const float2 axy = pxy[j]; const float az = pz[j];
      float h = fmaf(az - xiz, w15, fmaf(axy.y - xiy, w14, fmaf(axy.x - xix, w13, hbase)));
      h = fmaxf(h, 0.0f);
      unsigned short hbv, lbv; bfsplit(h, hbv, lbv);
      sh1[u*64 + (lane ^ ((u & 15) << 1))] = (unsigned)hbv | ((unsigned)lbv << 16);
    }
    asm volatile("s_waitcnt lgkmcnt(0)" ::: "memory");
    __builtin_amdgcn_sched_barrier(0);

    // MFMA: A row = edge (lanes 20..31 dup edge 0 -> max unchanged)
    const int ee = cl < 20 ? cl : 0;
    const int ebase = ee*64, esw = (ee & 15) << 1;
    f32x16 C0, C1;
    #pragma unroll
    for (int r = 0; r < 16; ++r) { C0[r] = 0.f; C1[r] = 0.f; }
    #pragma unroll
    for (int ks = 0; ks < 4; ++ks) {
      const int k8 = ks*16 + hi*8;
      const uint2 P0 = *(const uint2*)(sh1 + ebase + ((k8+0)^esw));
      const uint2 P1 = *(const uint2*)(sh1 + ebase + ((k8+2)^esw));
      const uint2 P2 = *(const uint2*)(sh1 + ebase + ((k8+4)^esw));
      const uint2 P3 = *(const uint2*)(sh1 + ebase + ((k8+6)^esw));
      union { bf16x8 v; unsigned u[4]; } Ah, Al;
      Ah.u[0] = (P0.x & 0xffffu) | (P0.y << 16);  Al.u[0] = (P0.x >> 16) | (P0.y & 0xffff0000u);
      Ah.u[1] = (P1.x & 0xffffu) | (P1.y << 16);  Al.u[1] = (P1.x >> 16) | (P1.y & 0xffff0000u);
      Ah.u[2] = (P2.x & 0xffffu) | (P2.y << 16);  Al.u[2] = (P2.x >> 16) | (P2.y & 0xffff0000u);
      Ah.u[3] = (P3.x & 0xffffu) | (P3.y << 16);  Al.u[3] = (P3.x >> 16) | (P3.y & 0xffff0000u);
      C0 = __builtin_amdgcn_mfma_f32_32x32x16_bf16(Ah.v, W2h[0][ks], C0, 0, 0, 0);
      C0 = __builtin_amdgcn_mfma_f32_32x32x16_bf16(Al.v, W2h[0][ks], C0, 0, 0, 0);
      C0 = __builtin_amdgcn_mfma_f32_32x32x16_bf16(Ah.v, W2l[0][ks], C0, 0, 0, 0);
      C1 = __builtin_amdgcn_mfma_f32_32x32x16_bf16(Ah.v, W2h[1][ks], C1, 0, 0, 0);
      C1 = __builtin_amdgcn_mfma_f32_32x32x16_bf16(Al.v, W2h[1][ks], C1, 0, 0, 0);
      C1 = __builtin_amdgcn_mfma_f32_32x32x16_bf16(Ah.v, W2l[1][ks], C1, 0, 0, 0);
    }
    float m0 = C0[0], m1v = C1[0];
    #pragma unroll
    for (int r = 1; r < 16; ++r) { m0 = fmaxf(m0, C0[r]); m1v = fmaxf(m1v, C1[r]); }
    m0  = fmaxf(m0,  __shfl_xor(m0, 32, 64));
    m1v = fmaxf(m1v, __shfl_xor(m1v, 32, 64));
    const float r0 = fmaxf(m0 + b2c0, 0.f);
    const float r1 = fmaxf(m1v + b2c1, 0.f);
    if (lane < 32) {
      out1[((size_t)b*NP + i)*64 + lane]      = r0;
      out1[((size_t)b*NP + i)*64 + 32 + lane] = r1;
    }
    float s = r0*r0 + r1*r1;
    #pragma unroll
    for (int m = 1; m < 32; m <<= 1) s += __shfl_xor(s, m, 64);
    if (lane == 0) nrm[b*NP + i] = s;
  }
}

// ---- EdgeConv2 kNN: split-bf16 MFMA dists + LDS redistribute + top-20 ----
__global__ __launch_bounds__(256) void ec2knn_kernel(
    const float* __restrict__ out1, const float* __restrict__ nrm,
    int* __restrict__ knn)
{
  __shared__ bf16x8 Bf[2][4][4][64];          // [pass][tile][ks][lane] 32 KB
  __shared__ float sdist[16][129];            // stride 129: conflict-spread
  __shared__ float snrm[128];
  __shared__ __align__(16) unsigned long long cpool[4][264];
  __shared__ __align__(16) float sbd[4][64];
  const int b = blockIdx.x, tid = threadIdx.x;
  const int wave = tid >> 6, lane = tid & 63;
  const int hi = lane >> 5, cl = lane & 31;
  const int pbase = blockIdx.y * 16;
  const float* xb = out1 + (size_t)b * NP * 64;
  // A fragments: 16 real rows dup'd to 32
  const int arow = pbase + (cl & 15);
  const float* ap = xb + (size_t)arow*64 + hi*8;
  bf16x8 Ahf[4], Alf[4];
  #pragma unroll
  for (int ks = 0; ks < 4; ++ks) {
    const float4 v0 = *(const float4*)(ap + ks*16);
    const float4 v1 = *(const float4*)(ap + ks*16 + 4);
    const float av[8] = {v0.x, v0.y, v0.z, v0.w, v1.x, v1.y, v1.z, v1.w};
    #pragma unroll
    for (int q = 0; q < 8; ++q) {
      unsigned short hbv, lbv; bfsplit(av[q], hbv, lbv);
      Ahf[ks][q] = (short)hbv; Alf[ks][q] = (short)lbv;
    }
  }
  const int p0 = pbase + wave*4;
  const float ni0 = nrm[b*NP + p0];
  const float ni1 = nrm[b*NP + p0 + 1];
  const float ni2 = nrm[b*NP + p0 + 2];
  const float ni3 = nrm[b*NP + p0 + 3];
  float d0[32], d1[32], d2[32], d3[32];
  #pragma unroll
  for (int ch = 0; ch < 16; ++ch) {
    __syncthreads();
    #pragma unroll
    for (int s4 = 0; s4 < 4; ++s4) {
      const int s = s4*256 + tid;
      const int tile = s >> 8, ksx = (s >> 6) & 3, l = s & 63;
      const int cand = ch*128 + tile*32 + (l & 31);
      const int kk = ksx*16 + ((l >> 5) << 3);
      const float* sp = xb + (size_t)cand*64 + kk;
      const float4 v0 = *(const float4*)(sp);
      const float4 v1 = *(const float4*)(sp + 4);
      const float av[8] = {v0.x, v0.y, v0.z, v0.w, v1.x, v1.y, v1.z, v1.w};
      bf16x8 vh, vl;
      #pragma unroll
      for (int q = 0; q < 8; ++q) {
        unsigned short hbv, lbv; bfsplit(av[q], hbv, lbv);
        vh[q] = (short)hbv; vl[q] = (short)lbv;
      }
      Bf[0][tile][ksx][l] = vh; Bf[1][tile][ksx][l] = vl;
    }
    if (tid < 128) snrm[tid] = nrm[b*NP + ch*128 + tid];
    __syncthreads();
    f32x16 C;
    #pragma unroll
    for (int r = 0; r < 16; ++r) C[r] = 0.f;
    #pragma unroll
    for (int ks = 0; ks < 4; ++ks) {
      const bf16x8 bh = Bf[0][wave][ks][lane];
      const bf16x8 bl = Bf[1][wave][ks][lane];
      C = __builtin_amdgcn_mfma_f32_32x32x16_bf16(Ahf[ks], bh, C, 0, 0, 0);
      C = __builtin_amdgcn_mfma_f32_32x32x16_bf16(Alf[ks], bh, C, 0, 0, 0);
      C = __builtin_amdgcn_mfma_f32_32x32x16_bf16(Ahf[ks], bl, C, 0, 0, 0);
    }
    #pragma unroll
    for (int r = 0; r < 8; ++r) {
      const int row = (r & 3) + 8*(r >> 2) + 4*hi;   // rows 0..15
      sdist[row][wave*32 + cl] = C[r];
    }
    __syncthreads();
    const float njA = snrm[lane], njB = snrm[64 + lane];
    d0[2*ch]   = ni0 + njA - 2.f*sdist[wave*4+0][lane];
    d0[2*ch+1] = ni0 + njB - 2.f*sdist[wave*4+0][64+lane];
    d1[2*ch]   = ni1 + njA - 2.f*sdist[wave*4+1][lane];
    d1[2*ch+1] = ni1 + njB - 2.f*sdist[wave*4+1][64+lane];
    d2[2*ch]   = ni2 + njA - 2.f*sdist[wave*4+2][lane];
    d2[2*ch+1] = ni2 + njB - 2.f*sdist[wave*4+2][64+lane];
    d3[2*ch]   = ni3 + njA - 2.f*sdist[wave*4+3][lane];
    d3[2*ch+1] = ni3 + njB - 2.f*sdist[wave*4+3][64+lane];
  }
  topk20(d0, lane, cpool[wave], sbd[wave], knn + ((size_t)b*NP + p0 + 0)*KNN);
  topk20(d1, lane, cpool[wave], sbd[wave], knn + ((size_t)b*NP + p0 + 1)*KNN);
  topk20(d2, lane, cpool[wave], sbd[wave], knn + ((size_t)b*NP + p0 + 2)*KNN);
  topk20(d3, lane, cpool[wave], sbd[wave], knn + ((size_t)b*NP + p0 + 3)*KNN);
}

// ---- base GEMM (MFMA): out2 <- bias + out1 @ W[0:64,:] ----
__global__ __launch_bounds__(256) void basegemm_kernel(
    const float* __restrict__ out1, const float* __restrict__ w,
    const float* __restrict__ bias, float* __restrict__ out2)
{
  const int b = blockIdx.x, tid = threadIdx.x;
  const int wave = tid >> 6, lane = tid & 63;
  const int hi = lane >> 5, cl = lane & 31;
  bf16x8 Wh[4], Wl[4];
  #pragma unroll
  for (int ks = 0; ks < 4; ++ks)
    #pragma unroll
    for (int idx = 0; idx < 8; ++idx) {
      const int k = ks*16 + hi*8 + idx;
      unsigned short hbv, lbv; bfsplit(w[(size_t)k*128 + wave*32 + cl], hbv, lbv);
      Wh[ks][idx] = (short)hbv; Wl[ks][idx] = (short)lbv;
    }
  const int row0 = blockIdx.y * 32;
  const float* ap = out1 + ((size_t)b*NP + row0 + cl)*64 + hi*8;
  bf16x8 Ah[4], Al[4];
  #pragma unroll
  for (int ks = 0; ks < 4; ++ks) {
    const float4 v0 = *(const float4*)(ap + ks*16);
    const float4 v1 = *(const float4*)(ap + ks*16 + 4);
    const float av[8] = {v0.x, v0.y, v0.z, v0.w, v1.x, v1.y, v1.z, v1.w};
    #pragma unroll
    for (int q = 0; q < 8; ++q) {
      unsigned short hbv, lbv; bfsplit(av[q], hbv, lbv);
      Ah[ks][q] = (short)hbv; Al[ks][q] = (short)lbv;
    }
  }
  f32x16 C;
  #pragma unroll
  for (int r = 0; r < 16; ++r) C[r] = 0.f;
  #pragma unroll
  for (int ks = 0; ks < 4; ++ks) {
    C = __builtin_amdgcn_mfma_f32_32x32x16_bf16(Ah[ks], Wh[ks], C, 0, 0, 0);
    C = __builtin_amdgcn_mfma_f32_32x32x16_bf16(Al[ks], Wh[ks], C, 0, 0, 0);
    C = __builtin_amdgcn_mfma_f32_32x32x16_bf16(Ah[ks], Wl[ks], C, 0, 0, 0);
  }
  const float bl = bias[wave*32 + cl];
  #pragma unroll
  for (int r = 0; r < 16; ++r) {
    const int row = (r & 3) + 8*(r >> 2) + 4*hi;
    out2[((size_t)b*NP + row0 + row)*128 + wave*32 + cl] = C[r] + bl;
  }
}

// ------- EdgeConv2 MLP neighbor part, split-bf16 MFMA, in-place on out2 -----
__global__ __launch_bounds__(256) void ec2mlp_kernel(
    const float* __restrict__ x, const int* __restrict__ knnIdx,
    const float* __restrict__ w, float* __restrict__ out2)
{
  __shared__ bf16x8 Bf[2][4][4][64];   // [pass][nt][ks][lane] 32 KB
  const int b = blockIdx.x, tid = threadIdx.x;
  const int wave = tid >> 6, lane = tid & 63;
  for (int s = tid; s < 2048; s += 256) {
    const int pass = s >> 10, nt = (s >> 8) & 3, ks = (s >> 6) & 3, l = s & 63;
    bf16x8 v;
    #pragma unroll
    for (int idx = 0; idx < 8; ++idx) {
      const int k = ks*16 + ((l >> 5) << 3) + idx;
      const float wv = w[(size_t)(64 + k)*128 + nt*32 + (l & 31)];
      unsigned short hb, lb; bfsplit(wv, hb, lb);
      v[idx] = (short)(pass ? lb : hb);
    }
    Bf[pass][nt][ks][l] = v;
  }
  __syncthreads();
  const float* xb = x + (size_t)b * NP * 64;
  #pragma unroll 1
  for (int p = 0; p < 8; ++p) {
    const int i = blockIdx.y*32 + wave*8 + p;
    const int e = lane & 31;
    const int* ip = knnIdx + ((size_t)b*NP + i)*KNN;
    const int j = ip[e < KNN ? e : 0];
    const float* xj = xb + (size_t)j*64 + ((lane >> 5) << 3);
    const float* xi = xb + (size_t)i*64 + ((lane >> 5) << 3);
    f32x16 C[4];
    #pragma unroll
    for (int nt = 0; nt < 4; ++nt)
      #pragma unroll
      for (int r = 0; r < 16; ++r) C[nt][r] = 0.f;
    #pragma unroll
    for (int ks = 0; ks < 4; ++ks) {
      const float4 j0 = *(const float4*)(xj + ks*16);
      const float4 j1 = *(const float4*)(xj + ks*16 + 4);
      const float4 i0 = *(const float4*)(xi + ks*16);
      const float4 i1 = *(const float4*)(xi + ks*16 + 4);
      const float dx[8] = { j0.x-i0.x, j0.y-i0.y, j0.z-i0.z, j0.w-i0.w,
                            j1.x-i1.x, j1.y-i1.y, j1.z-i1.z, j1.w-i1.w };
      bf16x8 Ah, Al;
      #pragma unroll
      for (int q = 0; q < 8; ++q) {
        unsigned short hb, lb; bfsplit(dx[q], hb, lb);
        Ah[q] = (short)hb; Al[q] = (short)lb;
      }
      #pragma unroll
      for (int nt = 0; nt < 4; ++nt) {
        const bf16x8 bh = Bf[0][nt][ks][lane];
        const bf16x8 bl = Bf[1][nt][ks][lane];
        C[nt] = __builtin_amdgcn_mfma_f32_32x32x16_bf16(Ah, bh, C[nt], 0, 0, 0);
        C[nt] = __builtin_amdgcn_mfma_f32_32x32x16_bf16(Al, bh, C[nt], 0, 0, 0);
        C[nt] = __builtin_amdgcn_mfma_f32_32x32x16_bf16(Ah, bl, C[nt], 0, 0, 0);
      }
    }
    #pragma unroll
    for (int nt = 0; nt < 4; ++nt) {
      float mx = C[nt][0];
      #pragma unroll
      for (int r = 1; r < 16; ++r) mx = fmaxf(mx, C[nt][r]);
      mx = fmaxf(mx, __shfl_xor(mx, 32, 64));
      const float basev = out2[((size_t)b*NP + i)*128 + nt*32 + (lane & 31)];
      const float res = fmaxf(mx + basev, 0.f);
      if (lane < 32) out2[((size_t)b*NP + i)*128 + nt*32 + lane] = res;
    }
  }
}

// ------- m1+pool: relu([out1|out2] @ W192x512 + b) row-summed, split-bf16 MFMA
__global__ __launch_bounds__(256) void m1pool_kernel(
    const float* __restrict__ o1, const float* __restrict__ o2,
    const float* __restrict__ w, const float* __restrict__ bias,
    float* __restrict__ pool)
{
  __shared__ bf16x8 Bf[2][2][12][64];  // [pass][nt][ks][lane] 48 KB
  const int b = blockIdx.x, tid = threadIdx.x;
  const int wave = tid >> 6, lane = tid & 63;
  const int colbase = blockIdx.y * 64;
  for (int s = tid; s < 3072; s += 256) {
    const int pass = s / 1536;
    const int r1 = s - pass*1536;
    const int nt = r1 / 768;
    const int r2 = r1 - nt*768;
    const int ks = r2 >> 6, l = r2 & 63;
    bf16x8 v;
    #pragma unroll
    for (int idx = 0; idx < 8; ++idx) {
      const int k = ks*16 + ((l >> 5) << 3) + idx;
      const float wv = w[(size_t)k*512 + colbase + nt*32 + (l & 31)];
      unsigned short hb, lb; bfsplit(wv, hb, lb);
      v[idx] = (short)(pass ? lb : hb);
    }
    Bf[pass][nt][ks][l] = v;
  }
  __syncthreads();
  const float bad0 = bias[colbase + (lane & 31)];
  const float bad1 = bias[colbase + 32 + (lane & 31)];
  float acc0 = 0.f, acc1 = 0.f;
  #pragma unroll 1
  for (int rt = 0; rt < 8; ++rt) {
    const int tile = blockIdx.z*32 + wave*8 + rt;
    const int row = tile*32 + (lane & 31);
    const float* a1 = o1 + ((size_t)b*NP + row)*64  + ((lane >> 5) << 3);
    const float* a2 = o2 + ((size_t)b*NP + row)*128 + ((lane >> 5) << 3);
    f32x16 C0, C1;
    #pragma unroll
    for (int r = 0; r < 16; ++r) { C0[r] = 0.f; C1[r] = 0.f; }
    #pragma unroll
    for (int ks = 0; ks < 12; ++ks) {
      const float* src = (ks < 4) ? (a1 + ks*16) : (a2 + (ks - 4)*16);
      const float4 v0 = *(const float4*)(src);
      const float4 v1 = *(const float4*)(src + 4);
      const float av[8] = { v0.x, v0.y, v0.z, v0.w, v1.x, v1.y, v1.z, v1.w };
      bf16x8 Ah, Al;
      #pragma unroll
      for (int q = 0; q < 8; ++q) {
        unsigned short hb, lb; bfsplit(av[q], hb, lb);
        Ah[q] = (short)hb; Al[q] = (short)lb;
      }
      {
        const bf16x8 bh = Bf[0][0][ks][lane];
        const bf16x8 bl = Bf[1][0][ks][lane];
        C0 = __builtin_amdgcn_mfma_f32_32x32x16_bf16(Ah, bh, C0, 0, 0, 0);
        C0 = __builtin_amdgcn_mfma_f32_32x32x16_bf16(Al, bh, C0, 0, 0, 0);
        C0 = __builtin_amdgcn_mfma_f32_32x32x16_bf16(Ah, bl, C0, 0, 0, 0);
      }
      {
        const bf16x8 bh = Bf[0][1][ks][lane];
        const bf16x8 bl = Bf[1][1][ks][lane];
        C1 = __builtin_amdgcn_mfma_f32_32x32x16_bf16(Ah, bh, C1, 0, 0, 0);
        C1 = __builtin_amdgcn_mfma_f32_32x32x16_bf16(Al, bh, C1, 0, 0, 0);
        C1 = __builtin_amdgcn_mfma_f32_32x32x16_bf16(Ah, bl, C1, 0, 0, 0);
      }
    }
    float s0 = 0.f, s1 = 0.f;
    #pragma unroll
    for (int r = 0; r < 16; ++r) {
      s0 += fmaxf(C0[r] + bad0, 0.f);
      s1 += fmaxf(C1[r] + bad1, 0.f);
    }
    acc0 += s0 + __shfl_xor(s0, 32, 64);
    acc1 += s1 + __shfl_xor(s1, 32, 64);
  }
  if (lane < 32) {
    atomicAdd(&pool[b*512 + colbase + lane], acc0);
    atomicAdd(&pool[b*512 + colbase + 32 + lane], acc1);
  }
}

// ---------------- head: mean -> 512 -> 256 -> 10 (fp32, tiny) ---------------
__global__ __launch_bounds__(256) void head_kernel(
    const float* __restrict__ pool,
    const float* __restrict__ w1, const float* __restrict__ b1,
    const float* __restrict__ w2, const float* __restrict__ b2,
    const float* __restrict__ w3, const float* __restrict__ b3,
    float* __restrict__ out)
{
  __shared__ float g0[512], g1[512], g2[256];
  const int b = blockIdx.x, t = threadIdx.x;
  for (int k = t; k < 512; k += 256) g0[k] = pool[b*512 + k] * (1.0f/2048.0f);
  __syncthreads();
  for (int o = t; o < 512; o += 256) {
    float s = b1[o];
    for (int c = 0; c < 512; ++c) s = fmaf(g0[c], w1[(size_t)c*512 + o], s);
    g1[o] = fmaxf(s, 0.f);
  }
  __syncthreads();
  if (t < 256) {
    float s = b2[t];
    for (int c = 0; c < 512; ++c) s = fmaf(g1[c], w2[(size_t)c*256 + t], s);
    g2[t] = fmaxf(s, 0.f);
  }
  __syncthreads();
  if (t < 10) {
    float s = b3[t];
    for (int c = 0; c < 256; ++c) s = fmaf(g2[c], w3[c*10 + t], s);
    out[b*10 + t] = s;
  }
}

extern "C" void kernel_launch(void* const* d_in, const int* in_sizes, int n_in,
                              void* d_out, int out_size, void* d_ws, size_t ws_size,
                              hipStream_t stream) {
  const float* pos  = (const float*)d_in[0];
  const float* c1w1 = (const float*)d_in[1];
  const float* c1b1 = (const float*)d_in[2];
  const float* c1w2 = (const float*)d_in[3];
  const float* c1b2 = (const float*)d_in[4];
  const float* c2w1 = (const float*)d_in[5];
  const float* c2b1 = (const float*)d_in[6];
  const float* m1w1 = (const float*)d_in[7];
  const float* m1b1 = (const float*)d_in[8];
  const float* m2w1 = (const float*)d_in[9];
  const float* m2b1 = (const float*)d_in[10];
  const float* m2w2 = (const float*)d_in[11];
  const float* m2b2 = (const float*)d_in[12];
  const float* m2w3 = (const float*)d_in[13];
  const float* m2b3 = (const float*)d_in[14];

  float* out1 = (float*)d_ws;                        // 16*2048*64
  float* out2 = out1 + (size_t)NB*NP*64;             // 16*2048*128
  float* nrm  = out2 + (size_t)NB*NP*128;            // 16*2048
  int*   knn  = (int*)(nrm + (size_t)NB*NP);         // 16*2048*20
  float* pool = (float*)(knn + (size_t)NB*NP*KNN);   // 16*512

  hipMemsetAsync(pool, 0, NB*512*sizeof(float), stream);
  ec1_kernel<<<dim3(NB, 64), 256, 0, stream>>>(pos, c1w1, c1b1, c1w2, c1b2, out1, nrm);
  ec2knn_kernel<<<dim3(NB, 128), 256, 0, stream>>>(out1, nrm, knn);
  basegemm_kernel<<<dim3(NB, 64), 256, 0, stream>>>(out1, c2w1, c2b1, out2);
  ec2mlp_kernel<<<dim3(NB, 64), 256, 0, stream>>>(out1, knn, c2w1, out2);
  m1pool_kernel<<<dim3(NB, 8, 2), 256, 0, stream>>>(out1, out2, m1w1, m1b1, pool);
  head_kernel<<<dim3(NB), 256, 0, stream>>>(pool, m2w1, m2b1, m2w2, m2b2, m2w3, m2b3,
                                            (float*)d_out);
}

// Round 9
// 605.717 us; speedup vs baseline: 4.7236x; 1.2889x over previous
//
#include <hip/hip_runtime.h>

#define NB 16
#define NP 2048
#define KNN 20
#define INFD 3.0e38f

typedef short bf16x8 __attribute__((ext_vector_type(8)));
typedef float f32x16 __attribute__((ext_vector_type(16)));

// monotonic float->uint key (handles tiny negative dists from fp cancellation)
__device__ __forceinline__ unsigned fkey(float f) {
  unsigned u = __float_as_uint(f);
  return (u & 0x80000000u) ? ~u : (u | 0x80000000u);
}

// fp32 -> bf16 RNE on raw bits (finite inputs)
__device__ __forceinline__ unsigned short f2bf(float f) {
  unsigned u = __float_as_uint(f);
  return (unsigned short)((u + 0x7fffu + ((u >> 16) & 1u)) >> 16);
}
// split x ~= hi + lo (each bf16); residual ~2^-16 * |x|
__device__ __forceinline__ void bfsplit(float f, unsigned short& h, unsigned short& l) {
  h = f2bf(f);
  l = f2bf(f - __uint_as_float((unsigned)h << 16));
}

// exact fallback only (pool overflow, ~never)
__device__ __forceinline__ void wave_argmin(float& d, int& j) {
  #pragma unroll
  for (int m = 1; m < 64; m <<= 1) {
    const float pd = __shfl_xor(d, m, 64);
    const int   pj = __shfl_xor(j, m, 64);
    if (pd < d || (pd == d && pj < j)) { d = pd; j = pj; }
  }
}

// top-20 of 2048 candidates; d[tt] is dist of candidate j = tt*64+lane.
// Exact-rank threshold on the 64 lane-mins; pool superset of top-20; rank-select.
__device__ __forceinline__ void topk20(float (&d)[32], const int lane,
                                       unsigned long long* __restrict__ pool,
                                       float* __restrict__ sbd,
                                       int* __restrict__ dst)
{
  float m16[16];
  #pragma unroll
  for (int t = 0; t < 16; ++t) m16[t] = fminf(d[2*t], d[2*t+1]);
  #pragma unroll
  for (int t = 0; t < 8; ++t) m16[t] = fminf(m16[t], m16[t+8]);
  #pragma unroll
  for (int t = 0; t < 4; ++t) m16[t] = fminf(m16[t], m16[t+4]);
  const float bd = fminf(fminf(m16[0], m16[2]), fminf(m16[1], m16[3]));

  sbd[lane] = bd;
  asm volatile("s_waitcnt lgkmcnt(0)" ::: "memory");
  __builtin_amdgcn_sched_barrier(0);
  int rk = 0;
  #pragma unroll
  for (int e = 0; e < 64; e += 4) {
    const float4 v = *(const float4*)(sbd + e);
    rk += (v.x < bd) + (v.y < bd) + (v.z < bd) + (v.w < bd);
  }
  float tb = (rk <= 19) ? bd : -INFD;
  #pragma unroll
  for (int m = 1; m < 64; m <<= 1) tb = fmaxf(tb, __shfl_xor(tb, m, 64));
  const float t = tb;

  int base = 0;
  #pragma unroll
  for (int tt = 0; tt < 32; ++tt) {
    const bool p = (d[tt] <= t);
    const unsigned long long mask = __ballot(p);
    if (p) {
      const int off = base + (int)__popcll(mask & ((1ull << lane) - 1ull));
      if (off < 256)
        pool[off] = ((unsigned long long)fkey(d[tt]) << 32) | (unsigned)(tt*64 + lane);
    }
    base += (int)__popcll(mask);
  }

  if (base <= 256) {
    const int n = base;
    if (lane == 0) { pool[n] = ~0ull; pool[n+1] = ~0ull; pool[n+2] = ~0ull; }
    asm volatile("s_waitcnt lgkmcnt(0)" ::: "memory");
    __builtin_amdgcn_sched_barrier(0);
    const int nn4 = (n + 3) & ~3;
    #pragma unroll 1
    for (int s = 0; s*64 < n; ++s) {
      const unsigned long long mykey = pool[s*64 + lane];
      int cnt = 0;
      #pragma unroll 1
      for (int e = 0; e < nn4; e += 4) {
        const ulonglong2 kA = *(const ulonglong2*)(pool + e);
        const ulonglong2 kB = *(const ulonglong2*)(pool + e + 2);
        cnt += (kA.x < mykey) ? 1 : 0;
        cnt += (kA.y < mykey) ? 1 : 0;
        cnt += (kB.x < mykey) ? 1 : 0;
        cnt += (kB.y < mykey) ? 1 : 0;
      }
      const int idx = s*64 + lane;
      if (idx < n && cnt < KNN)
        dst[cnt] = (int)(mykey & 0xffffffffu);
    }
  } else {
    #pragma unroll 1
    for (int nsel = 0; nsel < KNN; ++nsel) {
      float md = INFD; int mj = 0x7fffffff;
      #pragma unroll
      for (int tt = 0; tt < 32; ++tt)
        if (d[tt] < md) { md = d[tt]; mj = tt*64 + lane; }
      wave_argmin(md, mj);
      if (lane == 0) dst[nsel] = mj;
      #pragma unroll
      for (int tt = 0; tt < 32; ++tt)
        if (tt*64 + lane == mj) d[tt] = INFD;
    }
  }
  asm volatile("s_waitcnt lgkmcnt(0)" ::: "memory");
  __builtin_amdgcn_sched_barrier(0);
}

// ---- EdgeConv1: exact 3-dim kNN + MLP(6->64 VALU, 64->64 split-bf16 MFMA) ----
__global__ __launch_bounds__(256) void ec1_kernel(
    const float* __restrict__ pos, const float* __restrict__ w1,
    const float* __restrict__ b1, const float* __restrict__ w2,
    const float* __restrict__ b2, float* __restrict__ out1,
    float* __restrict__ nrm)
{
  __shared__ float2 pxy[NP];
  __shared__ float  pz[NP];
  __shared__ __align__(16) unsigned scratch[4][1280];
  __shared__ int sidx[4][20];
  const int b = blockIdx.x, tid = threadIdx.x;
  const int wave = tid >> 6, lane = tid & 63;
  const int hi = lane >> 5, cl = lane & 31;
  const float* pb = pos + (size_t)b * NP * 3;
  for (int k = tid; k < NP; k += 256) {
    pxy[k] = make_float2(pb[3*k], pb[3*k+1]); pz[k] = pb[3*k+2];
  }
  const float w10 = w1[0*64+lane], w11 = w1[1*64+lane], w12 = w1[2*64+lane];
  const float w13 = w1[3*64+lane], w14 = w1[4*64+lane], w15 = w1[5*64+lane];
  const float b1l = b1[lane];
  const float b2c0 = b2[cl], b2c1 = b2[32 + cl];
  bf16x8 W2h[2][4], W2l[2][4];
  #pragma unroll
  for (int nt = 0; nt < 2; ++nt)
    #pragma unroll
    for (int ks = 0; ks < 4; ++ks)
      #pragma unroll
      for (int idx = 0; idx < 8; ++idx) {
        const int k = ks*16 + hi*8 + idx;
        unsigned short hbv, lbv; bfsplit(w2[k*64 + nt*32 + cl], hbv, lbv);
        W2h[nt][ks][idx] = (short)hbv; W2l[nt][ks][idx] = (short)lbv;
      }
  __syncthreads();
  unsigned long long* pool = (unsigned long long*)scratch[wave];
  float* sbd = (float*)(scratch[wave] + 1024);
  unsigned* sh1 = scratch[wave];

  #pragma unroll 1
  for (int p = 0; p < 8; ++p) {
    const int i = blockIdx.y * 32 + wave * 8 + p;
    const float xix = pxy[i].x, xiy = pxy[i].y, xiz = pz[i];
    const float ni = xix*xix + xiy*xiy + xiz*xiz;
    float d[32];
    #pragma unroll
    for (int tt = 0; tt < 32; ++tt) {
      const int j = tt*64 + lane;
      const float2 axy = pxy[j];
      const float ax = axy.x, ay = axy.y, az = pz[j];
      const float nj = ax*ax + ay*ay + az*az;
      const float dot = xix*ax + xiy*ay + xiz*az;
      d[tt] = ni + nj - 2.0f*dot;
    }
    topk20(d, lane, pool, sbd, sidx[wave]);

    const int jreg = sidx[wave][cl < 20 ? cl : 0];
    const float hbase = fmaf(xiz, w12, fmaf(xiy, w11, fmaf(xix, w10, b1l)));
    #pragma unroll
    for (int u = 0; u < 20; ++u) {
      const int j = __builtin_amdgcn_readlane(jreg, u);
      const float2 axy = pxy[j]; const float az = pz[j];
      float h = fmaf(az - xiz, w15, fmaf(axy.y - xiy, w14, fmaf(axy.x - xix, w13, hbase)));
      h = fmaxf(h, 0.0f);
      unsigned short hbv, lbv; bfsplit(h, hbv, lbv);
      sh1[u*64 + (lane ^ ((u & 15) << 1))] = (unsigned)hbv | ((unsigned)lbv << 16);
    }
    asm volatile("s_waitcnt lgkmcnt(0)" ::: "memory");
    __builtin_amdgcn_sched_barrier(0);

    const int ee = cl < 20 ? cl : 0;
    const int ebase = ee*64, esw = (ee & 15) << 1;
    f32x16 C0, C1;
    #pragma unroll
    for (int r = 0; r < 16; ++r) { C0[r] = 0.f; C1[r] = 0.f; }
    #pragma unroll
    for (int ks = 0; ks < 4; ++ks) {
      const int k8 = ks*16 + hi*8;
      const uint2 P0 = *(const uint2*)(sh1 + ebase + ((k8+0)^esw));
      const uint2 P1 = *(const uint2*)(sh1 + ebase + ((k8+2)^esw));
      const uint2 P2 = *(const uint2*)(sh1 + ebase + ((k8+4)^esw));
      const uint2 P3 = *(const uint2*)(sh1 + ebase + ((k8+6)^esw));
      union { bf16x8 v; unsigned u[4]; } Ah, Al;
      Ah.u[0] = (P0.x & 0xffffu) | (P0.y << 16);  Al.u[0] = (P0.x >> 16) | (P0.y & 0xffff0000u);
      Ah.u[1] = (P1.x & 0xffffu) | (P1.y << 16);  Al.u[1] = (P1.x >> 16) | (P1.y & 0xffff0000u);
      Ah.u[2] = (P2.x & 0xffffu) | (P2.y << 16);  Al.u[2] = (P2.x >> 16) | (P2.y & 0xffff0000u);
      Ah.u[3] = (P3.x & 0xffffu) | (P3.y << 16);  Al.u[3] = (P3.x >> 16) | (P3.y & 0xffff0000u);
      C0 = __builtin_amdgcn_mfma_f32_32x32x16_bf16(Ah.v, W2h[0][ks], C0, 0, 0, 0);
      C0 = __builtin_amdgcn_mfma_f32_32x32x16_bf16(Al.v, W2h[0][ks], C0, 0, 0, 0);
      C0 = __builtin_amdgcn_mfma_f32_32x32x16_bf16(Ah.v, W2l[0][ks], C0, 0, 0, 0);
      C1 = __builtin_amdgcn_mfma_f32_32x32x16_bf16(Ah.v, W2h[1][ks], C1, 0, 0, 0);
      C1 = __builtin_amdgcn_mfma_f32_32x32x16_bf16(Al.v, W2h[1][ks], C1, 0, 0, 0);
      C1 = __builtin_amdgcn_mfma_f32_32x32x16_bf16(Ah.v, W2l[1][ks], C1, 0, 0, 0);
    }
    float m0 = C0[0], m1v = C1[0];
    #pragma unroll
    for (int r = 1; r < 16; ++r) { m0 = fmaxf(m0, C0[r]); m1v = fmaxf(m1v, C1[r]); }
    m0  = fmaxf(m0,  __shfl_xor(m0, 32, 64));
    m1v = fmaxf(m1v, __shfl_xor(m1v, 32, 64));
    const float r0 = fmaxf(m0 + b2c0, 0.f);
    const float r1 = fmaxf(m1v + b2c1, 0.f);
    if (lane < 32) {
      out1[((size_t)b*NP + i)*64 + lane]      = r0;
      out1[((size_t)b*NP + i)*64 + 32 + lane] = r1;
    }
    float s = r0*r0 + r1*r1;
    #pragma unroll
    for (int m = 1; m < 32; m <<= 1) s += __shfl_xor(s, m, 64);
    if (lane == 0) nrm[b*NP + i] = s;
  }
}

// ---- split: out1 -> packed split-bf16 MFMA fragments xsplit[pt][pass*8+g] ----
__global__ __launch_bounds__(256) void split_kernel(
    const float* __restrict__ x, bf16x8* __restrict__ xs)
{
  const int id = blockIdx.x * 256 + threadIdx.x;      // point index over NB*NP
  const float* r = x + (size_t)id * 64;
  bf16x8* dst = xs + (size_t)id * 16;
  #pragma unroll
  for (int g = 0; g < 8; ++g) {
    const float4 v0 = *(const float4*)(r + g*8);
    const float4 v1 = *(const float4*)(r + g*8 + 4);
    const float av[8] = {v0.x, v0.y, v0.z, v0.w, v1.x, v1.y, v1.z, v1.w};
    bf16x8 h, l;
    #pragma unroll
    for (int q = 0; q < 8; ++q) {
      unsigned short hb, lb; bfsplit(av[q], hb, lb);
      h[q] = (short)hb; l[q] = (short)lb;
    }
    dst[g] = h; dst[8 + g] = l;
  }
}

// ---- EdgeConv2 kNN: MFMA dists from precomputed xsplit + top-20 ----
__global__ __launch_bounds__(256) void ec2knn_kernel(
    const bf16x8* __restrict__ xs, const float* __restrict__ nrm,
    int* __restrict__ knn)
{
  __shared__ float sdist[16][129];            // stride 129: conflict-spread
  __shared__ float snrm[128];
  __shared__ __align__(16) unsigned long long cpool[4][264];
  __shared__ __align__(16) float sbd[4][64];
  const int b = blockIdx.x, tid = threadIdx.x;
  const int wave = tid >> 6, lane = tid & 63;
  const int hi = lane >> 5, cl = lane & 31;
  const int pbase = blockIdx.y * 16;
  const bf16x8* xsb = xs + (size_t)b * NP * 16;
  // A fragments: 16 real rows dup'd to 32, direct from xsplit
  const int arow = pbase + (cl & 15);
  bf16x8 Ahf[4], Alf[4];
  #pragma unroll
  for (int ks = 0; ks < 4; ++ks) {
    Ahf[ks] = xsb[(size_t)arow*16 + ks*2 + hi];
    Alf[ks] = xsb[(size_t)arow*16 + 8 + ks*2 + hi];
  }
  const int p0 = pbase + wave*4;
  const float ni0 = nrm[b*NP + p0];
  const float ni1 = nrm[b*NP + p0 + 1];
  const float ni2 = nrm[b*NP + p0 + 2];
  const float ni3 = nrm[b*NP + p0 + 3];
  float d0[32], d1[32], d2[32], d3[32];
  #pragma unroll 1
  for (int ch = 0; ch < 16; ++ch) {
    // B fragments: this wave's 32-cand tile, direct from xsplit (L2-resident)
    const int cand = ch*128 + wave*32 + cl;
    const bf16x8* cp = xsb + (size_t)cand*16;
    bf16x8 Bh[4], Bl[4];
    #pragma unroll
    for (int ks = 0; ks < 4; ++ks) { Bh[ks] = cp[ks*2 + hi]; Bl[ks] = cp[8 + ks*2 + hi]; }
    if (tid < 128) snrm[tid] = nrm[b*NP + ch*128 + tid];
    f32x16 C;
    #pragma unroll
    for (int r = 0; r < 16; ++r) C[r] = 0.f;
    #pragma unroll
    for (int ks = 0; ks < 4; ++ks) {
      C = __builtin_amdgcn_mfma_f32_32x32x16_bf16(Ahf[ks], Bh[ks], C, 0, 0, 0);
      C = __builtin_amdgcn_mfma_f32_32x32x16_bf16(Alf[ks], Bh[ks], C, 0, 0, 0);
      C = __builtin_amdgcn_mfma_f32_32x32x16_bf16(Ahf[ks], Bl[ks], C, 0, 0, 0);
    }
    #pragma unroll
    for (int r = 0; r < 8; ++r) {
      const int row = (r & 3) + 8*(r >> 2) + 4*hi;   // rows 0..15
      sdist[row][wave*32 + cl] = C[r];
    }
    __syncthreads();
    const float njA = snrm[lane], njB = snrm[64 + lane];
    d0[2*ch]   = ni0 + njA - 2.f*sdist[wave*4+0][lane];
    d0[2*ch+1] = ni0 + njB - 2.f*sdist[wave*4+0][64+lane];
    d1[2*ch]   = ni1 + njA - 2.f*sdist[wave*4+1][lane];
    d1[2*ch+1] = ni1 + njB - 2.f*sdist[wave*4+1][64+lane];
    d2[2*ch]   = ni2 + njA - 2.f*sdist[wave*4+2][lane];
    d2[2*ch+1] = ni2 + njB - 2.f*sdist[wave*4+2][64+lane];
    d3[2*ch]   = ni3 + njA - 2.f*sdist[wave*4+3][lane];
    d3[2*ch+1] = ni3 + njB - 2.f*sdist[wave*4+3][64+lane];
    __syncthreads();
  }
  topk20(d0, lane, cpool[wave], sbd[wave], knn + ((size_t)b*NP + p0 + 0)*KNN);
  topk20(d1, lane, cpool[wave], sbd[wave], knn + ((size_t)b*NP + p0 + 1)*KNN);
  topk20(d2, lane, cpool[wave], sbd[wave], knn + ((size_t)b*NP + p0 + 2)*KNN);
  topk20(d3, lane, cpool[wave], sbd[wave], knn + ((size_t)b*NP + p0 + 3)*KNN);
}

// ---- dual GEMM (MFMA): out2 <- bias + x@W[0:64,:] ; ybuf <- x@W[64:128,:] ----
__global__ __launch_bounds__(256) void basegemm_kernel(
    const bf16x8* __restrict__ xs, const float* __restrict__ w,
    const float* __restrict__ bias, float* __restrict__ out2,
    float* __restrict__ ybuf)
{
  const int b = blockIdx.x, tid = threadIdx.x;
  const int wave = tid >> 6, lane = tid & 63;
  const int hi = lane >> 5, cl = lane & 31;
  bf16x8 Wbh[4], Wbl[4], Wyh[4], Wyl[4];
  #pragma unroll
  for (int ks = 0; ks < 4; ++ks)
    #pragma unroll
    for (int idx = 0; idx < 8; ++idx) {
      const int k = ks*16 + hi*8 + idx;
      unsigned short hbv, lbv;
      bfsplit(w[(size_t)k*128 + wave*32 + cl], hbv, lbv);
      Wbh[ks][idx] = (short)hbv; Wbl[ks][idx] = (short)lbv;
      bfsplit(w[(size_t)(64 + k)*128 + wave*32 + cl], hbv, lbv);
      Wyh[ks][idx] = (short)hbv; Wyl[ks][idx] = (short)lbv;
    }
  const int row0 = blockIdx.y * 32;
  const bf16x8* ap = xs + ((size_t)b*NP + row0 + cl)*16;
  bf16x8 Ah[4], Al[4];
  #pragma unroll
  for (int ks = 0; ks < 4; ++ks) {
    Ah[ks] = ap[ks*2 + hi];
    Al[ks] = ap[8 + ks*2 + hi];
  }
  f32x16 Cb, Cy;
  #pragma unroll
  for (int r = 0; r < 16; ++r) { Cb[r] = 0.f; Cy[r] = 0.f; }
  #pragma unroll
  for (int ks = 0; ks < 4; ++ks) {
    Cb = __builtin_amdgcn_mfma_f32_32x32x16_bf16(Ah[ks], Wbh[ks], Cb, 0, 0, 0);
    Cb = __builtin_amdgcn_mfma_f32_32x32x16_bf16(Al[ks], Wbh[ks], Cb, 0, 0, 0);
    Cb = __builtin_amdgcn_mfma_f32_32x32x16_bf16(Ah[ks], Wbl[ks], Cb, 0, 0, 0);
    Cy = __builtin_amdgcn_mfma_f32_32x32x16_bf16(Ah[ks], Wyh[ks], Cy, 0, 0, 0);
    Cy = __builtin_amdgcn_mfma_f32_32x32x16_bf16(Al[ks], Wyh[ks], Cy, 0, 0, 0);
    Cy = __builtin_amdgcn_mfma_f32_32x32x16_bf16(Ah[ks], Wyl[ks], Cy, 0, 0, 0);
  }
  const float bl = bias[wave*32 + cl];
  #pragma unroll
  for (int r = 0; r < 16; ++r) {
    const int row = (r & 3) + 8*(r >> 2) + 4*hi;
    out2[((size_t)b*NP + row0 + row)*128 + wave*32 + cl] = Cb[r] + bl;
    ybuf[((size_t)b*NP + row0 + row)*128 + wave*32 + cl] = Cy[r];
  }
}

// ---- gather-max: out2[i] = relu(out2[i] - y[i] + max_{j in knn(i)} y[j]) ----
__global__ __launch_bounds__(256) void gathermax_kernel(
    const float* __restrict__ ybuf, const int* __restrict__ knnIdx,
    float* __restrict__ out2)
{
  const int b = blockIdx.x, tid = threadIdx.x;
  const int wave = tid >> 6, lane = tid & 63;
  const float2* yb2 = (const float2*)(ybuf + (size_t)b * NP * 128);
  #pragma unroll 1
  for (int q = 0; q < 4; ++q) {
    const int i = blockIdx.y*16 + wave*4 + q;
    const int* ip = knnIdx + ((size_t)b*NP + i)*KNN;
    float2 m = yb2[(size_t)ip[0]*64 + lane];
    #pragma unroll
    for (int e = 1; e < KNN; ++e) {
      const float2 v = yb2[(size_t)ip[e]*64 + lane];
      m.x = fmaxf(m.x, v.x); m.y = fmaxf(m.y, v.y);
    }
    float2* o2 = (float2*)(out2 + ((size_t)b*NP + i)*128);
    const float2 bv = o2[lane];
    const float2 yi = yb2[(size_t)i*64 + lane];
    float2 r;
    r.x = fmaxf(bv.x - yi.x + m.x, 0.f);
    r.y = fmaxf(bv.y - yi.y + m.y, 0.f);
    o2[lane] = r;
  }
}

// ------- m1+pool: relu([out1|out2] @ W192x512 + b) row-summed, split-bf16 MFMA
__global__ __launch_bounds__(256) void m1pool_kernel(
    const float* __restrict__ o1, const float* __restrict__ o2,
    const float* __restrict__ w, const float* __restrict__ bias,
    float* __restrict__ pool)
{
  __shared__ bf16x8 Bf[2][2][12][64];  // [pass][nt][ks][lane] 48 KB
  const int b = blockIdx.x, tid = threadIdx.x;
  const int wave = tid >> 6, lane = tid & 63;
  const int colbase = blockIdx.y * 64;
  for (int s = tid; s < 3072; s += 256) {
    const int pass = s / 1536;
    const int r1 = s - pass*1536;
    const int nt = r1 / 768;
    const int r2 = r1 - nt*768;
    const int ks = r2 >> 6, l = r2 & 63;
    bf16x8 v;
    #pragma unroll
    for (int idx = 0; idx < 8; ++idx) {
      const int k = ks*16 + ((l >> 5) << 3) + idx;
      const float wv = w[(size_t)k*512 + colbase + nt*32 + (l & 31)];
      unsigned short hb, lb; bfsplit(wv, hb, lb);
      v[idx] = (short)(pass ? lb : hb);
    }
    Bf[pass][nt][ks][l] = v;
  }
  __syncthreads();
  const float bad0 = bias[colbase + (lane & 31)];
  const float bad1 = bias[colbase + 32 + (lane & 31)];
  float acc0 = 0.f, acc1 = 0.f;
  #pragma unroll 1
  for (int rt = 0; rt < 8; ++rt) {
    const int tile = blockIdx.z*32 + wave*8 + rt;
    const int row = tile*32 + (lane & 31);
    const float* a1 = o1 + ((size_t)b*NP + row)*64  + ((lane >> 5) << 3);
    const float* a2 = o2 + ((size_t)b*NP + row)*128 + ((lane >> 5) << 3);
    f32x16 C0, C1;
    #pragma unroll
    for (int r = 0; r < 16; ++r) { C0[r] = 0.f; C1[r] = 0.f; }
    #pragma unroll
    for (int ks = 0; ks < 12; ++ks) {
      const float* src = (ks < 4) ? (a1 + ks*16) : (a2 + (ks - 4)*16);
      const float4 v0 = *(const float4*)(src);
      const float4 v1 = *(const float4*)(src + 4);
      const float av[8] = { v0.x, v0.y, v0.z, v0.w, v1.x, v1.y, v1.z, v1.w };
      bf16x8 Ah, Al;
      #pragma unroll
      for (int q = 0; q < 8; ++q) {
        unsigned short hb, lb; bfsplit(av[q], hb, lb);
        Ah[q] = (short)hb; Al[q] = (short)lb;
      }
      {
        const bf16x8 bh = Bf[0][0][ks][lane];
        const bf16x8 bl = Bf[1][0][ks][lane];
        C0 = __builtin_amdgcn_mfma_f32_32x32x16_bf16(Ah, bh, C0, 0, 0, 0);
        C0 = __builtin_amdgcn_mfma_f32_32x32x16_bf16(Al, bh, C0, 0, 0, 0);
        C0 = __builtin_amdgcn_mfma_f32_32x32x16_bf16(Ah, bl, C0, 0, 0, 0);
      }
      {
        const bf16x8 bh = Bf[0][1][ks][lane];
        const bf16x8 bl = Bf[1][1][ks][lane];
        C1 = __builtin_amdgcn_mfma_f32_32x32x16_bf16(Ah, bh, C1, 0, 0, 0);
        C1 = __builtin_amdgcn_mfma_f32_32x32x16_bf16(Al, bh, C1, 0, 0, 0);
        C1 = __builtin_amdgcn_mfma_f32_32x32x16_bf16(Ah, bl, C1, 0, 0, 0);
      }
    }
    float s0 = 0.f, s1 = 0.f;
    #pragma unroll
    for (int r = 0; r < 16; ++r) {
      s0 += fmaxf(C0[r] + bad0, 0.f);
      s1 += fmaxf(C1[r] + bad1, 0.f);
    }
    acc0 += s0 + __shfl_xor(s0, 32, 64);
    acc1 += s1 + __shfl_xor(s1, 32, 64);
  }
  if (lane < 32) {
    atomicAdd(&pool[b*512 + colbase + lane], acc0);
    atomicAdd(&pool[b*512 + colbase + 32 + lane], acc1);
  }
}

// ---------------- head: mean -> 512 -> 256 -> 10 (fp32, tiny) ---------------
__global__ __launch_bounds__(256) void head_kernel(
    const float* __restrict__ pool,
    const float* __restrict__ w1, const float* __restrict__ b1,
    const float* __restrict__ w2, const float* __restrict__ b2,
    const float* __restrict__ w3, const float* __restrict__ b3,
    float* __restrict__ out)
{
  __shared__ float g0[512], g1[512], g2[256];
  const int b = blockIdx.x, t = threadIdx.x;
  for (int k = t; k < 512; k += 256) g0[k] = pool[b*512 + k] * (1.0f/2048.0f);
  __syncthreads();
  for (int o = t; o < 512; o += 256) {
    float s = b1[o];
    for (int c = 0; c < 512; ++c) s = fmaf(g0[c], w1[(size_t)c*512 + o], s);
    g1[o] = fmaxf(s, 0.f);
  }
  __syncthreads();
  if (t < 256) {
    float s = b2[t];
    for (int c = 0; c < 512; ++c) s = fmaf(g1[c], w2[(size_t)c*256 + t], s);
    g2[t] = fmaxf(s, 0.f);
  }
  __syncthreads();
  if (t < 10) {
    float s = b3[t];
    for (int c = 0; c < 256; ++c) s = fmaf(g2[c], w3[c*10 + t], s);
    out[b*10 + t] = s;
  }
}

extern "C" void kernel_launch(void* const* d_in, const int* in_sizes, int n_in,
                              void* d_out, int out_size, void* d_ws, size_t ws_size,
                              hipStream_t stream) {
  const float* pos  = (const float*)d_in[0];
  const float* c1w1 = (const float*)d_in[1];
  const float* c1b1 = (const float*)d_in[2];
  const float* c1w2 = (const float*)d_in[3];
  const float* c1b2 = (const float*)d_in[4];
  const float* c2w1 = (const float*)d_in[5];
  const float* c2b1 = (const float*)d_in[6];
  const float* m1w1 = (const float*)d_in[7];
  const float* m1b1 = (const float*)d_in[8];
  const float* m2w1 = (const float*)d_in[9];
  const float* m2b1 = (const float*)d_in[10];
  const float* m2w2 = (const float*)d_in[11];
  const float* m2b2 = (const float*)d_in[12];
  const float* m2w3 = (const float*)d_in[13];
  const float* m2b3 = (const float*)d_in[14];

  float* out1   = (float*)d_ws;                          // 16*2048*64  (8 MB)
  float* out2   = out1 + (size_t)NB*NP*64;               // 16*2048*128 (16 MB)
  float* ybuf   = out2 + (size_t)NB*NP*128;              // 16*2048*128 (16 MB)
  float* nrm    = ybuf + (size_t)NB*NP*128;              // 16*2048
  int*   knn    = (int*)(nrm + (size_t)NB*NP);           // 16*2048*20
  float* pool   = (float*)(knn + (size_t)NB*NP*KNN);     // 16*512
  bf16x8* xsplit = (bf16x8*)(pool + (size_t)NB*512);     // 16*2048*256B (8 MB)

  hipMemsetAsync(pool, 0, NB*512*sizeof(float), stream);
  ec1_kernel<<<dim3(NB, 64), 256, 0, stream>>>(pos, c1w1, c1b1, c1w2, c1b2, out1, nrm);
  split_kernel<<<dim3(NB*NP/256), 256, 0, stream>>>(out1, xsplit);
  ec2knn_kernel<<<dim3(NB, 128), 256, 0, stream>>>(xsplit, nrm, knn);
  basegemm_kernel<<<dim3(NB, 64), 256, 0, stream>>>(xsplit, c2w1, c2b1, out2, ybuf);
  gathermax_kernel<<<dim3(NB, 128), 256, 0, stream>>>(ybuf, knn, out2);
  m1pool_kernel<<<dim3(NB, 8, 2), 256, 0, stream>>>(out1, out2, m1w1, m1b1, pool);
  head_kernel<<<dim3(NB), 256, 0, stream>>>(pool, m2w1, m2b1, m2w2, m2b2, m2w3, m2b3,
                                            (float*)d_out);
}